// Round 4
// baseline (413.563 us; speedup 1.0000x reference)
//
#include <hip/hip_runtime.h>
#include <cstdint>
#include <cstddef>

#define NN 500000            // nodes = 16 * 31250 exactly
#define NG 15625             // 32-node granules (2 tiles each; NN%32==0, no tail)
#define NBLK 1536            // 128-thread blocks
#define NWAVES (NBLK * 2)
// IN_CH=64, HEADS=4, OUT_CH=32, F=128 out feats, GH=256 gate hidden, SEGS=1024

typedef __attribute__((ext_vector_type(8))) short short8;   // 8 bf16 MFMA frag
typedef __attribute__((ext_vector_type(4))) float floatx4;  // MFMA accumulator
typedef __attribute__((ext_vector_type(4))) float fv4;

__device__ __forceinline__ unsigned short f2bf(float f) {
  union { float f; unsigned u; } v; v.f = f;
  unsigned r = v.u + 0x7FFFu + ((v.u >> 16) & 1u);  // RNE
  return (unsigned short)(r >> 16);
}
// HW packed f32->bf16 (RNE): low16 = a, high16 = b. 1 inst vs ~10 for manual.
__device__ __forceinline__ unsigned cvtpk(float a, float b) {
  unsigned r;
  asm("v_cvt_pk_bf16_f32 %0, %1, %2" : "=v"(r) : "v"(a), "v"(b));
  return r;
}
__device__ __forceinline__ fv4 ntload4(const float* p) {
  return __builtin_nontemporal_load((const fv4*)p);
}

#define MFMA16(a, b, c) __builtin_amdgcn_mfma_f32_16x16x32_bf16((a), (b), (c), 0, 0, 0)

// ---------------------------------------------------------------------------
// Kernel W: fp32 weights -> bf16 MFMA A-fragment order. gw2 gets a zero-padded
// 16-row A-fragment block (heads = rows 0-3) so gate L2 can run as MFMA.
// Also zeroes denom/out accumulators.
// dst[((frag)*64+lane)*8+j] = W[row(lane)][k(frag,lane,j)]
// ---------------------------------------------------------------------------
__global__ void swizzle_weights(const float* __restrict__ gw1, const float* __restrict__ mw1,
                                const float* __restrict__ mw2, const float* __restrict__ gw2,
                                unsigned short* __restrict__ gw1s,
                                unsigned short* __restrict__ mw1s,
                                unsigned short* __restrict__ mw2s,
                                unsigned short* __restrict__ gw2s,
                                float* __restrict__ denom, float* __restrict__ out) {
  int e = blockIdx.x * 256 + threadIdx.x;   // 45056 total
  if (e < 4096) denom[e] = 0.f;
#pragma unroll
  for (int i = 0; i < 3; ++i) {             // 131072 = 1024 segs * 128 fcols
    int o = e + i * 45056;
    if (o < 131072) out[o] = 0.f;
  }
  if (e >= 40960) {                         // gw2 [4][256] -> 8 frags, rows 4-15 = 0
    int local = e - 40960;                  // 4096
    int j = local & 7, lane = (local >> 3) & 63, frag = local >> 9;  // frag 0..7
    int row = lane & 15;
    int k = frag * 32 + ((lane >> 4) & 3) * 8 + j;   // 0..255
    gw2s[local] = (row < 4) ? f2bf(gw2[row * 256 + k]) : (unsigned short)0;
    return;
  }
  const float* src; unsigned short* dst; int ksteps, K, local;
  if (e < 16384)      { src = gw1; dst = gw1s; ksteps = 2; K = 64;  local = e; }
  else if (e < 24576) { src = mw1; dst = mw1s; ksteps = 2; K = 64;  local = e - 16384; }
  else                { src = mw2; dst = mw2s; ksteps = 4; K = 128; local = e - 24576; }
  int j = local & 7, lane = (local >> 3) & 63, tile = local >> 9;
  int ks = tile % ksteps, mtile = tile / ksteps;
  int row = mtile * 16 + (lane & 15);
  int k   = ks * 32 + ((lane >> 4) & 3) * 8 + j;
  dst[local] = f2bf(src[row * K + k]);
}

#define FLUSH() do {                                                          \
  _Pragma("unroll") for (int mt_ = 0; mt_ < 8; ++mt_) {                       \
    _Pragma("unroll") for (int r_ = 0; r_ < 4; ++r_) {                        \
      float v_ = acc[mt_][r_];                                                \
      v_ += __shfl_xor(v_, 1); v_ += __shfl_xor(v_, 2);                       \
      v_ += __shfl_xor(v_, 4); v_ += __shfl_xor(v_, 8);                       \
      if (lcol == 0)                                                          \
        atomicAdd(&out[cur_seg * 128 + mt_ * 16 + quad * 4 + r_], v_);        \
      acc[mt_][r_] = 0.f; } }                                                 \
  _Pragma("unroll") for (int h_ = 0; h_ < 4; ++h_) {                          \
    float v_ = e_sum[h_];                                                     \
    v_ += __shfl_xor(v_, 1); v_ += __shfl_xor(v_, 2);                         \
    v_ += __shfl_xor(v_, 4); v_ += __shfl_xor(v_, 8);                         \
    if (lane == 0) atomicAdd(&denom[cur_seg * 4 + h_], v_);                   \
    e_sum[h_] = 0.f; }                                                        \
} while (0)

// ---------------------------------------------------------------------------
// Fused kernel, fully barrier-free: each WAVE owns contiguous 32-node granules
// (2 tiles), processed per-tile so x-fragments are transient. Gate L2 now runs
// as MFMA via the shared hs staging buffer + zero-padded gw2s A-frags (result
// broadcast from quad 0); this removes the 450-VALU/tile fused gate-L2, the
// gw2L LDS and the only barrier. All f32->bf16 packing via v_cvt_pk_bf16_f32.
// NO min-waves launch bound: rounds 1-3 proved a forced budget splits the
// unified RF evenly (arch = budget/2 < live set) -> deterministic scratch
// spill (WRITE 453/167/94 MB). Let the allocator take ~what it needs.
// Segment accumulation in registers, uniform run-loop, flush on seg change.
// ---------------------------------------------------------------------------
__global__ __launch_bounds__(128) void fused_kernel(
    const float* __restrict__ x, const int* __restrict__ batch,
    const unsigned short* __restrict__ gw1s, const unsigned short* __restrict__ mw1s,
    const unsigned short* __restrict__ mw2s, const unsigned short* __restrict__ gw2s,
    const float* __restrict__ prelu_a, const float* __restrict__ b1,
    float* __restrict__ denom, float* __restrict__ out) {
  __shared__ unsigned short hs_all[2][16 * 132]; // per-wave staging, 2x4.2 KB
  const int t = threadIdx.x;
  const int wave = t >> 6, lane = t & 63;
  const int quad = lane >> 4, lcol = lane & 15;
  unsigned short* hs = hs_all[wave];

  const float slope = prelu_a[0];
  const int W = blockIdx.x * 2 + wave;
  const int g0 = (int)(((long long)W * NG) / NWAVES);
  const int g1 = (int)(((long long)(W + 1) * NG) / NWAVES);

  float acc[8][4];
  float e_sum[4] = {0.f, 0.f, 0.f, 0.f};
#pragma unroll
  for (int mt = 0; mt < 8; ++mt)
#pragma unroll
    for (int r = 0; r < 4; ++r) acc[mt][r] = 0.f;
  int fs = g0 * 32; if (fs > NN - 1) fs = NN - 1;
  int cur_seg = batch[fs];

  for (int g = g0; g < g1; ++g) {
    const int base = g * 32;
    int sv[2];
    float e16[2][4];
    union BH { short8 s; uint2 u[2]; } bh[2][4];

#pragma unroll
    for (int nt = 0; nt < 2; ++nt) {
      const int node = base + nt * 16 + lcol;   // NN%32==0 -> always valid
      sv[nt] = batch[node];
      const float* xp = x + (size_t)node * 64 + quad * 8;
      fv4 v0 = ntload4(xp), v1 = ntload4(xp + 4);
      fv4 v2 = ntload4(xp + 32), v3 = ntload4(xp + 36);
      union { short8 s; unsigned u[4]; } u0, u1;
      u0.u[0] = cvtpk(v0[0], v0[1]); u0.u[1] = cvtpk(v0[2], v0[3]);
      u0.u[2] = cvtpk(v1[0], v1[1]); u0.u[3] = cvtpk(v1[2], v1[3]);
      u1.u[0] = cvtpk(v2[0], v2[1]); u1.u[1] = cvtpk(v2[2], v2[3]);
      u1.u[2] = cvtpk(v3[0], v3[1]); u1.u[3] = cvtpk(v3[2], v3[3]);
      const short8 bx0 = u0.s, bx1 = u1.s;

      // ---- gate: L1 MFMA + PReLU -> bf16 staging; L2 MFMA with gw2s ----
      floatx4 cg = {0.f, 0.f, 0.f, 0.f};
#pragma unroll
      for (int c = 0; c < 2; ++c) {
#pragma unroll 2
        for (int mt = 0; mt < 8; ++mt) {
          const int fm = c * 8 + mt;
          short8 a0 = *(const short8*)(gw1s + ((size_t)(fm * 2 + 0) * 64 + lane) * 8);
          short8 a1 = *(const short8*)(gw1s + ((size_t)(fm * 2 + 1) * 64 + lane) * 8);
          floatx4 cc = {0.f, 0.f, 0.f, 0.f};
          cc = MFMA16(a0, bx0, cc);
          cc = MFMA16(a1, bx1, cc);
          float h0 = cc[0] >= 0.f ? cc[0] : slope * cc[0];
          float h1v = cc[1] >= 0.f ? cc[1] : slope * cc[1];
          float h2 = cc[2] >= 0.f ? cc[2] : slope * cc[2];
          float h3 = cc[3] >= 0.f ? cc[3] : slope * cc[3];
          uint2 p;
          p.x = cvtpk(h0, h1v);
          p.y = cvtpk(h2, h3);
          *(uint2*)(hs + lcol * 132 + mt * 16 + quad * 4) = p;
        }
#pragma unroll
        for (int ks = 0; ks < 4; ++ks) {
          short8 ga = *(const short8*)(gw2s + ((size_t)(c * 4 + ks) * 64 + lane) * 8);
          union { short8 s; uint2 u[2]; } bg;
          const unsigned short* hp = hs + lcol * 132 + ks * 32 + quad * 8;
          bg.u[0] = *(const uint2*)hp;
          bg.u[1] = *(const uint2*)(hp + 4);
          cg = MFMA16(ga, bg.s, cg);
        }
      }
      // heads live in quad 0 (rows 0-3), col = node; broadcast + exp
#pragma unroll
      for (int h = 0; h < 4; ++h)
        e16[nt][h] = __expf(__shfl(cg[h], lcol));  // |gate| small -> no max

      // ---- MLP L1 (MFMA) -> bf16 staging -> B-fragments for L2 ----
#pragma unroll 2
      for (int mt = 0; mt < 8; ++mt) {
        short8 a0 = *(const short8*)(mw1s + ((size_t)(mt * 2 + 0) * 64 + lane) * 8);
        short8 a1 = *(const short8*)(mw1s + ((size_t)(mt * 2 + 1) * 64 + lane) * 8);
        fv4 bias = *(const fv4*)(b1 + mt * 16 + quad * 4);
        floatx4 cc = {0.f, 0.f, 0.f, 0.f};
        cc = MFMA16(a0, bx0, cc);
        cc = MFMA16(a1, bx1, cc);
        uint2 p;
        p.x = cvtpk(fmaxf(cc[0] + bias[0], 0.f), fmaxf(cc[1] + bias[1], 0.f));
        p.y = cvtpk(fmaxf(cc[2] + bias[2], 0.f), fmaxf(cc[3] + bias[3], 0.f));
        *(uint2*)(hs + lcol * 132 + mt * 16 + quad * 4) = p;
      }
#pragma unroll
      for (int ks = 0; ks < 4; ++ks) {
        const unsigned short* hp = hs + lcol * 132 + ks * 32 + quad * 8;
        bh[nt][ks].u[0] = *(const uint2*)hp;
        bh[nt][ks].u[1] = *(const uint2*)(hp + 4);
      }
    }

    // ---- uniform run loop over segments within the 32 nodes ----
    int p = 0;
    while (p < 32) {
      int sel = (p >> 4) ? sv[1] : sv[0];
      int s = __shfl(sel, p & 15);       // seg of first unprocessed node (uniform)
      if (s != cur_seg) { FLUSH(); cur_seg = s; }
      int cnt = 0;
      float em[2][4];
#pragma unroll
      for (int nt = 0; nt < 2; ++nt) {
        bool mm = (sv[nt] == s);
        cnt += (int)__popcll(__ballot(mm));
        float m = mm ? 1.f : 0.f;
#pragma unroll
        for (int h = 0; h < 4; ++h) em[nt][h] = e16[nt][h] * m;
      }
#pragma unroll
      for (int h = 0; h < 4; ++h)
        e_sum[h] += em[0][h] + em[1][h];
#pragma unroll
      for (int mt = 0; mt < 8; ++mt) {
        short8 a20 = *(const short8*)(mw2s + ((size_t)(mt * 4 + 0) * 64 + lane) * 8);
        short8 a21 = *(const short8*)(mw2s + ((size_t)(mt * 4 + 1) * 64 + lane) * 8);
        short8 a22 = *(const short8*)(mw2s + ((size_t)(mt * 4 + 2) * 64 + lane) * 8);
        short8 a23 = *(const short8*)(mw2s + ((size_t)(mt * 4 + 3) * 64 + lane) * 8);
        const int hh = mt >> 1;          // head of fcols [mt*16, mt*16+16)
#pragma unroll
        for (int nt = 0; nt < 2; ++nt) {
          floatx4 cc = {0.f, 0.f, 0.f, 0.f};
          cc = MFMA16(a20, bh[nt][0].s, cc);
          cc = MFMA16(a21, bh[nt][1].s, cc);
          cc = MFMA16(a22, bh[nt][2].s, cc);
          cc = MFMA16(a23, bh[nt][3].s, cc);
          float e = em[nt][hh];
          acc[mt][0] = fmaf(e, cc[0], acc[mt][0]);
          acc[mt][1] = fmaf(e, cc[1], acc[mt][1]);
          acc[mt][2] = fmaf(e, cc[2], acc[mt][2]);
          acc[mt][3] = fmaf(e, cc[3], acc[mt][3]);
        }
      }
      p += (cnt >> 2);                   // 4 quads replicate each node
    }
  }
  FLUSH();
}

// ---------------------------------------------------------------------------
// Finalize: out = numer/denom + b2 (b2 separable; scores sum to 1 per seg-head)
// ---------------------------------------------------------------------------
__global__ void finalize_kernel(float* __restrict__ out, const float* __restrict__ denom,
                                const float* __restrict__ b2) {
  int i = blockIdx.x * 256 + threadIdx.x;   // 131072 = 1024 segs * 128 fcols
  int seg = i >> 7, head = (i >> 5) & 3;
  float d = denom[seg * 4 + head];
  out[i] = (d > 0.f) ? (out[i] / d + b2[i & 127]) : 0.f;
}

// ---------------------------------------------------------------------------
extern "C" void kernel_launch(void* const* d_in, const int* in_sizes, int n_in,
                              void* d_out, int out_size, void* d_ws, size_t ws_size,
                              hipStream_t stream) {
  const float* x     = (const float*)d_in[0];
  const int*   batch = (const int*)d_in[1];
  // d_in[2] = num_segments (constant 1024, unused)
  const float* gw1 = (const float*)d_in[3];
  const float* pa  = (const float*)d_in[4];
  const float* gw2 = (const float*)d_in[5];
  const float* mw1 = (const float*)d_in[6];
  const float* mb1 = (const float*)d_in[7];
  const float* mw2 = (const float*)d_in[8];
  const float* mb2 = (const float*)d_in[9];
  float* out = (float*)d_out;

  char* ws = (char*)d_ws;
  float* denom = (float*)ws;                              // 4096 fp32 = 16,384 B
  unsigned short* gw1s = (unsigned short*)(ws + 16384);   // 32,768 B
  unsigned short* mw1s = (unsigned short*)(ws + 49152);   // 16,384 B
  unsigned short* mw2s = (unsigned short*)(ws + 65536);   // 32,768 B
  unsigned short* gw2s = (unsigned short*)(ws + 98304);   //  8,192 B

  swizzle_weights<<<176, 256, 0, stream>>>(gw1, mw1, mw2, gw2,
                                           gw1s, mw1s, mw2s, gw2s, denom, out);

  fused_kernel<<<NBLK, 128, 0, stream>>>(x, batch, gw1s, mw1s, mw2s, gw2s,
                                         pa, mb1, denom, out);

  finalize_kernel<<<512, 256, 0, stream>>>(out, denom, mb2);
}

// Round 5
// 372.601 us; speedup vs baseline: 1.1099x; 1.1099x over previous
//
#include <hip/hip_runtime.h>
#include <cstdint>
#include <cstddef>

#define NN 500000            // nodes = 16 * 31250 exactly
#define NG 15625             // 32-node granules (2 tiles each; NN%32==0, no tail)
#define NBLK 2048            // 128-thread blocks; 8/CU resident -> 16 waves/CU
#define NWAVES (NBLK * 2)
// IN_CH=64, HEADS=4, OUT_CH=32, F=128 out feats, GH=256 gate hidden, SEGS=1024

typedef __attribute__((ext_vector_type(8))) short short8;   // 8 bf16 MFMA frag
typedef __attribute__((ext_vector_type(4))) float floatx4;  // MFMA accumulator
typedef __attribute__((ext_vector_type(4))) float fv4;

__device__ __forceinline__ unsigned short f2bf(float f) {
  union { float f; unsigned u; } v; v.f = f;
  unsigned r = v.u + 0x7FFFu + ((v.u >> 16) & 1u);  // RNE
  return (unsigned short)(r >> 16);
}
// HW packed f32->bf16 (RNE): low16 = a, high16 = b. 1 inst vs ~10 for manual.
__device__ __forceinline__ unsigned cvtpk(float a, float b) {
  unsigned r;
  asm("v_cvt_pk_bf16_f32 %0, %1, %2" : "=v"(r) : "v"(a), "v"(b));
  return r;
}
__device__ __forceinline__ fv4 ntload4(const float* p) {
  return __builtin_nontemporal_load((const fv4*)p);
}

#define MFMA16(a, b, c) __builtin_amdgcn_mfma_f32_16x16x32_bf16((a), (b), (c), 0, 0, 0)

// ---------------------------------------------------------------------------
// Kernel W: fp32 weights -> bf16 MFMA A-fragment order (gw1 / mw1 / mw2 only;
// gw2 is consumed as fp32 via LDS in the fused kernel). Also zeroes the
// denom/out accumulators (folds the two hipMemsetAsync launches).
// dst[((mtile*ksteps+ks)*64+lane)*8+j] = W[mtile*16+(lane&15)][ks*32+(lane>>4)*8+j]
// ---------------------------------------------------------------------------
__global__ void swizzle_weights(const float* __restrict__ gw1, const float* __restrict__ mw1,
                                const float* __restrict__ mw2,
                                unsigned short* __restrict__ gw1s,
                                unsigned short* __restrict__ mw1s,
                                unsigned short* __restrict__ mw2s,
                                float* __restrict__ denom, float* __restrict__ out) {
  int e = blockIdx.x * 256 + threadIdx.x;   // 40960 total
  if (e < 4096) denom[e] = 0.f;
#pragma unroll
  for (int i = 0; i < 4; ++i) {             // 131072 = 1024 segs * 128 fcols
    int o = e + i * 40960;
    if (o < 131072) out[o] = 0.f;
  }
  const float* src; unsigned short* dst; int ksteps, K, local;
  if (e < 16384)      { src = gw1; dst = gw1s; ksteps = 2; K = 64;  local = e; }
  else if (e < 24576) { src = mw1; dst = mw1s; ksteps = 2; K = 64;  local = e - 16384; }
  else                { src = mw2; dst = mw2s; ksteps = 4; K = 128; local = e - 24576; }
  int j = local & 7, lane = (local >> 3) & 63, tile = local >> 9;
  int ks = tile % ksteps, mtile = tile / ksteps;
  int row = mtile * 16 + (lane & 15);
  int k   = ks * 32 + ((lane >> 4) & 3) * 8 + j;
  dst[local] = f2bf(src[row * K + k]);
}

#define FLUSH() do {                                                          \
  _Pragma("unroll") for (int mt_ = 0; mt_ < 8; ++mt_) {                       \
    _Pragma("unroll") for (int r_ = 0; r_ < 4; ++r_) {                        \
      float v_ = acc[mt_][r_];                                                \
      v_ += __shfl_xor(v_, 1); v_ += __shfl_xor(v_, 2);                       \
      v_ += __shfl_xor(v_, 4); v_ += __shfl_xor(v_, 8);                       \
      if (lcol == 0)                                                          \
        atomicAdd(&out[cur_seg * 128 + mt_ * 16 + quad * 4 + r_], v_);        \
      acc[mt_][r_] = 0.f; } }                                                 \
  _Pragma("unroll") for (int h_ = 0; h_ < 4; ++h_) {                          \
    float v_ = e_sum[h_];                                                     \
    v_ += __shfl_xor(v_, 1); v_ += __shfl_xor(v_, 2);                         \
    v_ += __shfl_xor(v_, 4); v_ += __shfl_xor(v_, 8);                         \
    if (lane == 0) atomicAdd(&denom[cur_seg * 4 + h_], v_);                   \
    e_sum[h_] = 0.f; }                                                        \
} while (0)

// ---------------------------------------------------------------------------
// Fused kernel, one barrier (gw2L prologue): each WAVE owns contiguous 32-node
// granules (2 tiles). Weights streamed from global (L2-resident; x is
// nontemporal so it can't evict them). Gate L2 fused into gate L1 epilogue in
// VALU via gw2^T in LDS. MLP-L1 staging is per-16-node-tile (4.2 KB/wave).
// Register law measured over rounds 0-4: with MFMA present,
// __launch_bounds__(128,k) -> arch VGPRs = (512/k)/2 (128/84/64 for k=2/3/4);
// unbounded -> 172 all-VGPR (2 waves/SIMD, occupancy collapse, round 4).
// Live set ~130 => k=2 is the unique spill-free-ish + occupancy-friendly
// point: 128 arch VGPRs, 4 waves/SIMD, LDS 12.8 KB -> 8 blocks/CU resident.
// Segment accumulation in registers, uniform run-loop, flush on seg change.
// ---------------------------------------------------------------------------
__global__ __launch_bounds__(128, 2) void fused_kernel(
    const float* __restrict__ x, const int* __restrict__ batch,
    const unsigned short* __restrict__ gw1s, const unsigned short* __restrict__ mw1s,
    const unsigned short* __restrict__ mw2s, const float* __restrict__ gw2,
    const float* __restrict__ prelu_a, const float* __restrict__ b1,
    float* __restrict__ denom, float* __restrict__ out) {
  __shared__ float gw2L[1024];                   // gw2^T [wcol][head], 4 KB
  __shared__ unsigned short hs_all[2][16 * 132]; // per-wave h1 staging, 2x4.2 KB
  const int t = threadIdx.x;
  const int wave = t >> 6, lane = t & 63;
  const int quad = lane >> 4, lcol = lane & 15;
  unsigned short* hs = hs_all[wave];

  for (int i = t; i < 1024; i += 128) gw2L[i] = gw2[(i & 3) * 256 + (i >> 2)];
  __syncthreads();   // only barrier in the kernel

  const float slope = prelu_a[0];
  const int W = blockIdx.x * 2 + wave;
  const int g0 = (int)(((long long)W * NG) / NWAVES);
  const int g1 = (int)(((long long)(W + 1) * NG) / NWAVES);

  float acc[8][4];
  float e_sum[4] = {0.f, 0.f, 0.f, 0.f};
#pragma unroll
  for (int mt = 0; mt < 8; ++mt)
#pragma unroll
    for (int r = 0; r < 4; ++r) acc[mt][r] = 0.f;
  int fs = g0 * 32; if (fs > NN - 1) fs = NN - 1;
  int cur_seg = batch[fs];

  for (int g = g0; g < g1; ++g) {
    const int base = g * 32;
    int sv[2];
    short8 bx[2][2];
#pragma unroll
    for (int nt = 0; nt < 2; ++nt) {
      int node = base + nt * 16 + lcol;    // NN%32==0 -> always valid
      sv[nt] = batch[node];
      const float* xp = x + (size_t)node * 64 + quad * 8;
      fv4 v0 = ntload4(xp), v1 = ntload4(xp + 4);
      fv4 v2 = ntload4(xp + 32), v3 = ntload4(xp + 36);
      union { short8 s; unsigned u[4]; } u0, u1;
      u0.u[0] = cvtpk(v0[0], v0[1]); u0.u[1] = cvtpk(v0[2], v0[3]);
      u0.u[2] = cvtpk(v1[0], v1[1]); u0.u[3] = cvtpk(v1[2], v1[3]);
      u1.u[0] = cvtpk(v2[0], v2[1]); u1.u[1] = cvtpk(v2[2], v2[3]);
      u1.u[2] = cvtpk(v3[0], v3[1]); u1.u[3] = cvtpk(v3[2], v3[3]);
      bx[nt][0] = u0.s; bx[nt][1] = u1.s;
    }

    // ---- gate L1 (MFMA) with fused L2 partials (VALU, gw2L broadcast) ----
    float gp[2][4];
#pragma unroll
    for (int nt = 0; nt < 2; ++nt)
#pragma unroll
      for (int h = 0; h < 4; ++h) gp[nt][h] = 0.f;
#pragma unroll 2
    for (int mt = 0; mt < 16; ++mt) {
      short8 a0 = *(const short8*)(gw1s + ((size_t)(mt * 2 + 0) * 64 + lane) * 8);
      short8 a1 = *(const short8*)(gw1s + ((size_t)(mt * 2 + 1) * 64 + lane) * 8);
      fv4 g2r0 = *(const fv4*)&gw2L[(mt * 16 + quad * 4 + 0) * 4];
      fv4 g2r1 = *(const fv4*)&gw2L[(mt * 16 + quad * 4 + 1) * 4];
      fv4 g2r2 = *(const fv4*)&gw2L[(mt * 16 + quad * 4 + 2) * 4];
      fv4 g2r3 = *(const fv4*)&gw2L[(mt * 16 + quad * 4 + 3) * 4];
#pragma unroll
      for (int nt = 0; nt < 2; ++nt) {
        floatx4 cc = {0.f, 0.f, 0.f, 0.f};
        cc = MFMA16(a0, bx[nt][0], cc);
        cc = MFMA16(a1, bx[nt][1], cc);
        float h0 = cc[0] >= 0.f ? cc[0] : slope * cc[0];
        float h1v = cc[1] >= 0.f ? cc[1] : slope * cc[1];
        float h2 = cc[2] >= 0.f ? cc[2] : slope * cc[2];
        float h3 = cc[3] >= 0.f ? cc[3] : slope * cc[3];
        gp[nt][0] += g2r0[0]*h0 + g2r1[0]*h1v + g2r2[0]*h2 + g2r3[0]*h3;
        gp[nt][1] += g2r0[1]*h0 + g2r1[1]*h1v + g2r2[1]*h2 + g2r3[1]*h3;
        gp[nt][2] += g2r0[2]*h0 + g2r1[2]*h1v + g2r2[2]*h2 + g2r3[2]*h3;
        gp[nt][3] += g2r0[3]*h0 + g2r1[3]*h1v + g2r2[3]*h2 + g2r3[3]*h3;
      }
    }
    float e16[2][4];
#pragma unroll
    for (int nt = 0; nt < 2; ++nt)
#pragma unroll
      for (int h = 0; h < 4; ++h) {
        float v = gp[nt][h];
        v += __shfl_xor(v, 16);      // sum partials across quads
        v += __shfl_xor(v, 32);
        e16[nt][h] = __expf(v);      // |gate| small -> no max needed
      }

    // ---- MLP L1 (MFMA) -> per-tile bf16 staging -> B-fragments for L2 ----
    // nt-outer so the staging buffer covers only 16 nodes (LDS 4.2 KB/wave);
    // wave-internal LDS ordering handles the write->read->overwrite chain.
    union BH { short8 s; uint2 u[2]; } bh[2][4];
#pragma unroll
    for (int nt = 0; nt < 2; ++nt) {
#pragma unroll 2
      for (int mt = 0; mt < 8; ++mt) {
        short8 a0 = *(const short8*)(mw1s + ((size_t)(mt * 2 + 0) * 64 + lane) * 8);
        short8 a1 = *(const short8*)(mw1s + ((size_t)(mt * 2 + 1) * 64 + lane) * 8);
        fv4 bias = *(const fv4*)(b1 + mt * 16 + quad * 4);
        floatx4 cc = {0.f, 0.f, 0.f, 0.f};
        cc = MFMA16(a0, bx[nt][0], cc);
        cc = MFMA16(a1, bx[nt][1], cc);
        uint2 p;
        p.x = cvtpk(fmaxf(cc[0] + bias[0], 0.f), fmaxf(cc[1] + bias[1], 0.f));
        p.y = cvtpk(fmaxf(cc[2] + bias[2], 0.f), fmaxf(cc[3] + bias[3], 0.f));
        *(uint2*)(hs + lcol * 132 + mt * 16 + quad * 4) = p;
      }
#pragma unroll
      for (int ks = 0; ks < 4; ++ks) {
        const unsigned short* hp = hs + lcol * 132 + ks * 32 + quad * 8;
        bh[nt][ks].u[0] = *(const uint2*)hp;
        bh[nt][ks].u[1] = *(const uint2*)(hp + 4);
      }
    }

    // ---- uniform run loop over segments within the 32 nodes ----
    int p = 0;
    while (p < 32) {
      int sel = (p >> 4) ? sv[1] : sv[0];
      int s = __shfl(sel, p & 15);       // seg of first unprocessed node (uniform)
      if (s != cur_seg) { FLUSH(); cur_seg = s; }
      int cnt = 0;
      float em[2][4];
#pragma unroll
      for (int nt = 0; nt < 2; ++nt) {
        bool mm = (sv[nt] == s);
        cnt += (int)__popcll(__ballot(mm));
        float m = mm ? 1.f : 0.f;
#pragma unroll
        for (int h = 0; h < 4; ++h) em[nt][h] = e16[nt][h] * m;
      }
#pragma unroll
      for (int h = 0; h < 4; ++h)
        e_sum[h] += em[0][h] + em[1][h];
#pragma unroll
      for (int mt = 0; mt < 8; ++mt) {
        short8 a20 = *(const short8*)(mw2s + ((size_t)(mt * 4 + 0) * 64 + lane) * 8);
        short8 a21 = *(const short8*)(mw2s + ((size_t)(mt * 4 + 1) * 64 + lane) * 8);
        short8 a22 = *(const short8*)(mw2s + ((size_t)(mt * 4 + 2) * 64 + lane) * 8);
        short8 a23 = *(const short8*)(mw2s + ((size_t)(mt * 4 + 3) * 64 + lane) * 8);
        const int hh = mt >> 1;          // head of fcols [mt*16, mt*16+16)
#pragma unroll
        for (int nt = 0; nt < 2; ++nt) {
          floatx4 cc = {0.f, 0.f, 0.f, 0.f};
          cc = MFMA16(a20, bh[nt][0].s, cc);
          cc = MFMA16(a21, bh[nt][1].s, cc);
          cc = MFMA16(a22, bh[nt][2].s, cc);
          cc = MFMA16(a23, bh[nt][3].s, cc);
          float e = em[nt][hh];
          acc[mt][0] = fmaf(e, cc[0], acc[mt][0]);
          acc[mt][1] = fmaf(e, cc[1], acc[mt][1]);
          acc[mt][2] = fmaf(e, cc[2], acc[mt][2]);
          acc[mt][3] = fmaf(e, cc[3], acc[mt][3]);
        }
      }
      p += (cnt >> 2);                   // 4 quads replicate each node
    }
  }
  FLUSH();
}

// ---------------------------------------------------------------------------
// Finalize: out = numer/denom + b2 (b2 separable; scores sum to 1 per seg-head)
// ---------------------------------------------------------------------------
__global__ void finalize_kernel(float* __restrict__ out, const float* __restrict__ denom,
                                const float* __restrict__ b2) {
  int i = blockIdx.x * 256 + threadIdx.x;   // 131072 = 1024 segs * 128 fcols
  int seg = i >> 7, head = (i >> 5) & 3;
  float d = denom[seg * 4 + head];
  out[i] = (d > 0.f) ? (out[i] / d + b2[i & 127]) : 0.f;
}

// ---------------------------------------------------------------------------
extern "C" void kernel_launch(void* const* d_in, const int* in_sizes, int n_in,
                              void* d_out, int out_size, void* d_ws, size_t ws_size,
                              hipStream_t stream) {
  const float* x     = (const float*)d_in[0];
  const int*   batch = (const int*)d_in[1];
  // d_in[2] = num_segments (constant 1024, unused)
  const float* gw1 = (const float*)d_in[3];
  const float* pa  = (const float*)d_in[4];
  const float* gw2 = (const float*)d_in[5];
  const float* mw1 = (const float*)d_in[6];
  const float* mb1 = (const float*)d_in[7];
  const float* mw2 = (const float*)d_in[8];
  const float* mb2 = (const float*)d_in[9];
  float* out = (float*)d_out;

  char* ws = (char*)d_ws;
  float* denom = (float*)ws;                              // 4096 fp32 = 16,384 B
  unsigned short* gw1s = (unsigned short*)(ws + 16384);   // 32,768 B
  unsigned short* mw1s = (unsigned short*)(ws + 49152);   // 16,384 B
  unsigned short* mw2s = (unsigned short*)(ws + 65536);   // 32,768 B

  swizzle_weights<<<160, 256, 0, stream>>>(gw1, mw1, mw2, gw1s, mw1s, mw2s,
                                           denom, out);

  fused_kernel<<<NBLK, 128, 0, stream>>>(x, batch, gw1s, mw1s, mw2s, gw2,
                                         pa, mb1, denom, out);

  finalize_kernel<<<512, 256, 0, stream>>>(out, denom, mb2);
}

// Round 6
// 298.049 us; speedup vs baseline: 1.3876x; 1.2501x over previous
//
#include <hip/hip_runtime.h>
#include <cstdint>
#include <cstddef>

#define NN 500000            // nodes; NN%32==0 -> no tail
#define NG 15625             // 32-node granules
#define NBLK 1536            // 128-thread blocks; 3 waves/SIMD resident target
#define NWAVES (NBLK * 2)
// IN_CH=64, HEADS=4, OUT_CH=32, F=128 mlp hidden, GH=256 gate hidden, SEGS=1024

typedef __attribute__((ext_vector_type(8))) short short8;   // 8 bf16 MFMA frag
typedef __attribute__((ext_vector_type(4))) float floatx4;  // MFMA accumulator
typedef __attribute__((ext_vector_type(4))) float fv4;

__device__ __forceinline__ unsigned short f2bf(float f) {
  union { float f; unsigned u; } v; v.f = f;
  unsigned r = v.u + 0x7FFFu + ((v.u >> 16) & 1u);  // RNE
  return (unsigned short)(r >> 16);
}
__device__ __forceinline__ unsigned cvtpk(float a, float b) {
  unsigned r;
  asm("v_cvt_pk_bf16_f32 %0, %1, %2" : "=v"(r) : "v"(a), "v"(b));
  return r;
}
__device__ __forceinline__ fv4 ntload4(const float* p) {
  return __builtin_nontemporal_load((const fv4*)p);
}
__device__ __forceinline__ float bflo(unsigned u) {  // low bf16 -> f32
  union { unsigned u; float f; } v; v.u = u << 16; return v.f;
}
__device__ __forceinline__ float bfhi(unsigned u) {  // high bf16 -> f32
  union { unsigned u; float f; } v; v.u = u & 0xffff0000u; return v.f;
}

#define MFMA16(a, b, c) __builtin_amdgcn_mfma_f32_16x16x32_bf16((a), (b), (c), 0, 0, 0)

// ---------------------------------------------------------------------------
// Kernel W: gw1/mw1 fp32 -> bf16 MFMA fragment order (both K=64, 2 ksteps).
// Same fragment formula serves gw1 as A (rows=gate-hid) and mw1 as B
// (cols=fcol) since A/B per-lane index patterns are identical.
// Also zeroes denom (4 KB) and Z accumulator (2 MB). mw2 stays fp32 (finalize).
// ---------------------------------------------------------------------------
__global__ void swizzle_weights(const float* __restrict__ gw1, const float* __restrict__ mw1,
                                unsigned short* __restrict__ gw1s,
                                unsigned short* __restrict__ mw1s,
                                float* __restrict__ denom, float* __restrict__ zws) {
  int e = blockIdx.x * 256 + threadIdx.x;   // 24576 total
  if (e < 4096) denom[e] = 0.f;
#pragma unroll
  for (int i = 0; i < 22; ++i) {            // 524288 = 1024 segs * 4 h * 128 k
    int o = e + i * 24576;
    if (o < 524288) zws[o] = 0.f;
  }
  const float* src; unsigned short* dst; int local;
  if (e < 16384) { src = gw1; dst = gw1s; local = e; }
  else           { src = mw1; dst = mw1s; local = e - 16384; }
  int j = local & 7, lane = (local >> 3) & 63, tile = local >> 9;
  int ks = tile & 1, mtile = tile >> 1;
  int row = mtile * 16 + (lane & 15);
  int k   = ks * 32 + ((lane >> 4) & 3) * 8 + j;
  dst[local] = f2bf(src[row * 64 + k]);
}

// FLUSH: Z rows live in quad 0 (D rows 0-3 = heads); es reduced across quads.
#define FLUSH() do {                                                          \
  if (quad == 0) {                                                            \
    _Pragma("unroll") for (int mt_ = 0; mt_ < 8; ++mt_)                       \
      _Pragma("unroll") for (int r_ = 0; r_ < 4; ++r_)                        \
        atomicAdd(&zws[((size_t)cur_seg * 4 + r_) * 128 + mt_ * 16 + lcol],   \
                  acc[mt_][r_]);                                              \
  }                                                                           \
  _Pragma("unroll") for (int mt_ = 0; mt_ < 8; ++mt_)                         \
    acc[mt_] = (floatx4){0.f, 0.f, 0.f, 0.f};                                 \
  { float v_ = es; v_ += __shfl_xor(v_, 16); v_ += __shfl_xor(v_, 32);        \
    if (lane < 4) atomicAdd(&denom[cur_seg * 4 + lane], v_); }                \
  es = 0.f;                                                                   \
} while (0)

// ---------------------------------------------------------------------------
// Fused kernel. Per 32-node granule:
//   1. x -> bf16 frags bx (lane=node, serves as gate-B AND mlp1-A).
//   2. gate L1 MFMA + VALU-fused gate L2 (gw2^T in LDS) -> e16[nt][h].
//   3. MLP L1 operand-SWAPPED: D[node][fcol] (A=x, B=mw1s). relu+bias, cvtpk,
//      cross-quad shuffle-redistribute into zb[mt] = B-frag [k=node][col=fcol].
//   4. Run loop: masked E A-frag (rows=heads, k=32 nodes) from shuffled
//      e-values; ONE rank-32 MFMA per mt accumulates Z[h][fcol] per segment.
//      denom accumulated from the SAME bf16-rounded e (consistent softmax).
// MLP L2 is linear => hoisted out: out[seg] = mw2 * Z[seg]/denom + b2 in a
// tiny fp32 finalize kernel (16.8 MFLOP vs 16.4 GFLOP in-loop before).
// This deletes bh regs (-32), run-loop mw2s loads, and 3/4 of run MFMAs:
// live set ~95 arch + 32 AGPR -> spill-free at (128,2), 3 waves/SIMD.
// ---------------------------------------------------------------------------
__global__ __launch_bounds__(128, 2) void fused_kernel(
    const float* __restrict__ x, const int* __restrict__ batch,
    const unsigned short* __restrict__ gw1s, const unsigned short* __restrict__ mw1s,
    const float* __restrict__ gw2, const float* __restrict__ prelu_a,
    const float* __restrict__ b1, float* __restrict__ denom,
    float* __restrict__ zws) {
  __shared__ float gw2L[1024];                   // gw2^T [wcol][head], 4 KB
  const int t = threadIdx.x;
  const int wave = t >> 6, lane = t & 63;
  const int quad = lane >> 4, lcol = lane & 15;

  for (int i = t; i < 1024; i += 128) gw2L[i] = gw2[(i & 3) * 256 + (i >> 2)];
  __syncthreads();   // only barrier in the kernel

  const float slope = prelu_a[0];
  const int W = blockIdx.x * 2 + wave;
  const int g0 = (int)(((long long)W * NG) / NWAVES);
  const int g1 = (int)(((long long)(W + 1) * NG) / NWAVES);

  float b1v[8];
#pragma unroll
  for (int mt = 0; mt < 8; ++mt) b1v[mt] = b1[mt * 16 + lcol];  // bias per fcol

  floatx4 acc[8];                       // Z accumulator (AGPR): [mt] x 4 head-rows
#pragma unroll
  for (int mt = 0; mt < 8; ++mt) acc[mt] = (floatx4){0.f, 0.f, 0.f, 0.f};
  float es = 0.f;                       // denom accumulator (bf16-consistent)
  int fs = g0 * 32; if (fs > NN - 1) fs = NN - 1;
  int cur_seg = batch[fs];

  for (int g = g0; g < g1; ++g) {
    const int base = g * 32;
    int sv[2];
    short8 bx[2][2];
#pragma unroll
    for (int nt = 0; nt < 2; ++nt) {
      int node = base + nt * 16 + lcol;
      sv[nt] = batch[node];
      const float* xp = x + (size_t)node * 64 + quad * 8;
      fv4 v0 = ntload4(xp), v1 = ntload4(xp + 4);
      fv4 v2 = ntload4(xp + 32), v3 = ntload4(xp + 36);
      union { short8 s; unsigned u[4]; } u0, u1;
      u0.u[0] = cvtpk(v0[0], v0[1]); u0.u[1] = cvtpk(v0[2], v0[3]);
      u0.u[2] = cvtpk(v1[0], v1[1]); u0.u[3] = cvtpk(v1[2], v1[3]);
      u1.u[0] = cvtpk(v2[0], v2[1]); u1.u[1] = cvtpk(v2[2], v2[3]);
      u1.u[2] = cvtpk(v3[0], v3[1]); u1.u[3] = cvtpk(v3[2], v3[3]);
      bx[nt][0] = u0.s; bx[nt][1] = u1.s;
    }

    // ---- gate L1 (MFMA) with fused L2 partials (VALU, gw2L broadcast) ----
    float gp[2][4];
#pragma unroll
    for (int nt = 0; nt < 2; ++nt)
#pragma unroll
      for (int h = 0; h < 4; ++h) gp[nt][h] = 0.f;
#pragma unroll 2
    for (int mt = 0; mt < 16; ++mt) {
      short8 a0 = *(const short8*)(gw1s + ((size_t)(mt * 2 + 0) * 64 + lane) * 8);
      short8 a1 = *(const short8*)(gw1s + ((size_t)(mt * 2 + 1) * 64 + lane) * 8);
      fv4 g2r0 = *(const fv4*)&gw2L[(mt * 16 + quad * 4 + 0) * 4];
      fv4 g2r1 = *(const fv4*)&gw2L[(mt * 16 + quad * 4 + 1) * 4];
      fv4 g2r2 = *(const fv4*)&gw2L[(mt * 16 + quad * 4 + 2) * 4];
      fv4 g2r3 = *(const fv4*)&gw2L[(mt * 16 + quad * 4 + 3) * 4];
#pragma unroll
      for (int nt = 0; nt < 2; ++nt) {
        floatx4 cc = {0.f, 0.f, 0.f, 0.f};
        cc = MFMA16(a0, bx[nt][0], cc);
        cc = MFMA16(a1, bx[nt][1], cc);
        float h0 = cc[0] >= 0.f ? cc[0] : slope * cc[0];
        float h1v = cc[1] >= 0.f ? cc[1] : slope * cc[1];
        float h2 = cc[2] >= 0.f ? cc[2] : slope * cc[2];
        float h3 = cc[3] >= 0.f ? cc[3] : slope * cc[3];
        gp[nt][0] += g2r0[0]*h0 + g2r1[0]*h1v + g2r2[0]*h2 + g2r3[0]*h3;
        gp[nt][1] += g2r0[1]*h0 + g2r1[1]*h1v + g2r2[1]*h2 + g2r3[1]*h3;
        gp[nt][2] += g2r0[2]*h0 + g2r1[2]*h1v + g2r2[2]*h2 + g2r3[2]*h3;
        gp[nt][3] += g2r0[3]*h0 + g2r1[3]*h1v + g2r2[3]*h2 + g2r3[3]*h3;
      }
    }
    float e16[2][4];
#pragma unroll
    for (int nt = 0; nt < 2; ++nt)
#pragma unroll
      for (int h = 0; h < 4; ++h) {
        float v = gp[nt][h];
        v += __shfl_xor(v, 16);      // sum partials across quads
        v += __shfl_xor(v, 32);
        e16[nt][h] = __expf(v);      // |gate| small -> no max needed
      }

    // ---- MLP L1 swapped (D[node][fcol]) -> zb[mt] B-frags [k=node][fcol] ----
    union BH { short8 s; unsigned u[4]; } zb[8];
#pragma unroll
    for (int mt = 0; mt < 8; ++mt) {
      short8 w0 = *(const short8*)(mw1s + ((size_t)(mt * 2 + 0) * 64 + lane) * 8);
      short8 w1 = *(const short8*)(mw1s + ((size_t)(mt * 2 + 1) * 64 + lane) * 8);
      float bb = b1v[mt];
      unsigned pk[2][2];
#pragma unroll
      for (int nt = 0; nt < 2; ++nt) {
        floatx4 cc = {0.f, 0.f, 0.f, 0.f};
        cc = MFMA16(bx[nt][0], w0, cc);   // A = x (rows=node), B = mw1 (cols=fcol)
        cc = MFMA16(bx[nt][1], w1, cc);
        float h0 = fmaxf(cc[0] + bb, 0.f), h1v = fmaxf(cc[1] + bb, 0.f);
        float h2 = fmaxf(cc[2] + bb, 0.f), h3 = fmaxf(cc[3] + bb, 0.f);
        pk[nt][0] = cvtpk(h0, h1v);       // nodes nt*16+quad*4+{0,1}
        pk[nt][1] = cvtpk(h2, h3);        // nodes nt*16+quad*4+{2,3}
      }
      // redistribute: dst lane (quad,lcol) reg jj wants nodes quad*8+2jj,+1
      // at fcol=lcol. src quad = (quad&1)*2 + (jj>>1); piece = jj&1;
      // nt_src = quad>>1 (lane-varying -> select both shuffles).
#pragma unroll
      for (int jj = 0; jj < 4; ++jj) {
        int src = ((quad & 1) * 2 + (jj >> 1)) * 16 + lcol;
        unsigned v0 = __shfl(pk[0][jj & 1], src);
        unsigned v1 = __shfl(pk[1][jj & 1], src);
        zb[mt].u[jj] = (quad < 2) ? v0 : v1;
      }
    }

    // ---- per-granule E-source transpose: ev[j] = e(node=quad*8+j, h=lcol),
    //      svb[j] = seg(node=quad*8+j) ----
    float ev[8]; int svb[8];
#pragma unroll
    for (int j = 0; j < 8; ++j) {
      int m = (quad & 1) * 8 + j;                 // node & 15
      int s0 = __shfl(sv[0], m), s1 = __shfl(sv[1], m);
      svb[j] = (quad < 2) ? s0 : s1;
      float a0 = __shfl(e16[0][0], m), b0 = __shfl(e16[1][0], m);
      float a1 = __shfl(e16[0][1], m), b1x = __shfl(e16[1][1], m);
      float a2 = __shfl(e16[0][2], m), b2x = __shfl(e16[1][2], m);
      float a3 = __shfl(e16[0][3], m), b3 = __shfl(e16[1][3], m);
      float v0 = (quad < 2) ? a0 : b0;
      float v1 = (quad < 2) ? a1 : b1x;
      float v2 = (quad < 2) ? a2 : b2x;
      float v3 = (quad < 2) ? a3 : b3;
      float c01 = (lcol & 1) ? v1 : v0;
      float c23 = (lcol & 1) ? v3 : v2;
      ev[j] = (lcol & 2) ? c23 : c01;
    }

    // ---- run loop over segments within the 32 nodes ----
    int p = 0;
    while (p < 32) {
      int selv = (p >> 4) ? sv[1] : sv[0];
      int s = __shfl(selv, p & 15);     // seg of first unprocessed node (uniform)
      if (s != cur_seg) { FLUSH(); cur_seg = s; }
      int cnt = (int)__popcll(__ballot(sv[0] == s)) +
                (int)__popcll(__ballot(sv[1] == s));
      // masked E A-frag: row=h (lcol<4), k=node
      union { unsigned u[4]; short8 s8; } ea;
#pragma unroll
      for (int jj = 0; jj < 4; ++jj) {
        float e0 = (lcol < 4 && svb[2 * jj] == s) ? ev[2 * jj] : 0.f;
        float e1 = (lcol < 4 && svb[2 * jj + 1] == s) ? ev[2 * jj + 1] : 0.f;
        ea.u[jj] = cvtpk(e0, e1);
        es += bflo(ea.u[jj]) + bfhi(ea.u[jj]);   // denom from SAME rounded e
      }
#pragma unroll
      for (int mt = 0; mt < 8; ++mt)
        acc[mt] = MFMA16(ea.s8, zb[mt].s, acc[mt]);
      p += (cnt >> 2);                  // 4 quads replicate each node
    }
  }
  FLUSH();
}

// ---------------------------------------------------------------------------
// Finalize (fp32, exact): out[seg,fcol] = mw2[fcol,:].Z[seg,h(fcol),:]/denom
//                                         + b2[fcol]   (h = fcol>>5)
// One block per segment; Z row (512 f32) staged in LDS; 131k threads total.
// ---------------------------------------------------------------------------
__global__ __launch_bounds__(128) void finalize_kernel(
    const float* __restrict__ zws, const float* __restrict__ denom,
    const float* __restrict__ mw2, const float* __restrict__ b2,
    float* __restrict__ out) {
  __shared__ float zL[512];
  const int seg = blockIdx.x, t = threadIdx.x;
#pragma unroll
  for (int i = 0; i < 4; ++i) zL[t + i * 128] = zws[(size_t)seg * 512 + t + i * 128];
  __syncthreads();
  const int fcol = t, h = t >> 5;
  float d = denom[seg * 4 + h];
  const fv4* mrow = (const fv4*)(mw2 + (size_t)fcol * 128);
  const fv4* zrow = (const fv4*)(zL + h * 128);
  float a0 = 0.f, a1 = 0.f, a2 = 0.f, a3 = 0.f;
#pragma unroll 8
  for (int k = 0; k < 32; ++k) {
    fv4 w = mrow[k], z = zrow[k];
    a0 = fmaf(w[0], z[0], a0); a1 = fmaf(w[1], z[1], a1);
    a2 = fmaf(w[2], z[2], a2); a3 = fmaf(w[3], z[3], a3);
  }
  float acc = (a0 + a1) + (a2 + a3);
  out[(size_t)seg * 128 + fcol] = (d > 0.f) ? (acc / d + b2[fcol]) : 0.f;
}

// ---------------------------------------------------------------------------
extern "C" void kernel_launch(void* const* d_in, const int* in_sizes, int n_in,
                              void* d_out, int out_size, void* d_ws, size_t ws_size,
                              hipStream_t stream) {
  const float* x     = (const float*)d_in[0];
  const int*   batch = (const int*)d_in[1];
  // d_in[2] = num_segments (constant 1024, unused)
  const float* gw1 = (const float*)d_in[3];
  const float* pa  = (const float*)d_in[4];
  const float* gw2 = (const float*)d_in[5];
  const float* mw1 = (const float*)d_in[6];
  const float* mb1 = (const float*)d_in[7];
  const float* mw2 = (const float*)d_in[8];
  const float* mb2 = (const float*)d_in[9];
  float* out = (float*)d_out;

  char* ws = (char*)d_ws;
  float* denom = (float*)ws;                              // 16,384 B
  unsigned short* gw1s = (unsigned short*)(ws + 16384);   // 32,768 B
  unsigned short* mw1s = (unsigned short*)(ws + 49152);   // 16,384 B
  float* zws = (float*)(ws + 65536);                      // 2,097,152 B (Z)

  swizzle_weights<<<96, 256, 0, stream>>>(gw1, mw1, gw1s, mw1s, denom, zws);

  fused_kernel<<<NBLK, 128, 0, stream>>>(x, batch, gw1s, mw1s, gw2,
                                         pa, mb1, denom, zws);

  finalize_kernel<<<1024, 128, 0, stream>>>(zws, denom, mw2, mb2, out);
}

// Round 7
// 267.255 us; speedup vs baseline: 1.5474x; 1.1152x over previous
//
#include <hip/hip_runtime.h>
#include <cstdint>
#include <cstddef>

#define NN 500000            // nodes; NN%32==0 -> no tail
#define NG 15625             // 32-node granules
#define NBLK 1536            // 128-thread blocks; 6/CU, 3 waves/SIMD target
#define NWAVES (NBLK * 2)
// IN_CH=64, HEADS=4, OUT_CH=32, F=128 mlp hidden, GH=256 gate hidden, SEGS=1024

typedef __attribute__((ext_vector_type(8))) short short8;   // 8 bf16 MFMA frag
typedef __attribute__((ext_vector_type(4))) float floatx4;  // MFMA accumulator
typedef __attribute__((ext_vector_type(4))) float fv4;

__device__ __forceinline__ unsigned short f2bf(float f) {
  union { float f; unsigned u; } v; v.f = f;
  unsigned r = v.u + 0x7FFFu + ((v.u >> 16) & 1u);  // RNE
  return (unsigned short)(r >> 16);
}
__device__ __forceinline__ unsigned cvtpk(float a, float b) {
  unsigned r;
  asm("v_cvt_pk_bf16_f32 %0, %1, %2" : "=v"(r) : "v"(a), "v"(b));
  return r;
}
__device__ __forceinline__ fv4 ntload4(const float* p) {
  return __builtin_nontemporal_load((const fv4*)p);
}
__device__ __forceinline__ float bflo(unsigned u) {  // low bf16 -> f32
  union { unsigned u; float f; } v; v.u = u << 16; return v.f;
}
__device__ __forceinline__ float bfhi(unsigned u) {  // high bf16 -> f32
  union { unsigned u; float f; } v; v.u = u & 0xffff0000u; return v.f;
}

#define MFMA16(a, b, c) __builtin_amdgcn_mfma_f32_16x16x32_bf16((a), (b), (c), 0, 0, 0)

// ---------------------------------------------------------------------------
// Kernel W: fp32 -> bf16 MFMA fragment order.
//  gw1s/mw1s: standard A/B fragment layout (K=64, 2 ksteps each).
//  gw2s: sigma-g permuted A-fragments for the MFMA gate-L2: frag s, k-element
//  (quad*8+j) holds w = s*32 + (j<4?0:16) + 4*quad + (j&3); rows 4-15 zero.
//  This matches the k-order in which gate-L1's PReLU epilogue naturally holds
//  its outputs (D rows quad*4+r of mt=2s,2s+1) -> zero-shuffle B assembly.
// Also zeroes denom (16 KB) and Z accumulator (2 MB).
// ---------------------------------------------------------------------------
__global__ void swizzle_weights(const float* __restrict__ gw1, const float* __restrict__ mw1,
                                const float* __restrict__ gw2,
                                unsigned short* __restrict__ gw1s,
                                unsigned short* __restrict__ mw1s,
                                unsigned short* __restrict__ gw2s,
                                float* __restrict__ denom, float* __restrict__ zws) {
  int e = blockIdx.x * 256 + threadIdx.x;   // 28672 total
  if (e < 4096) denom[e] = 0.f;
#pragma unroll
  for (int i = 0; i < 19; ++i) {            // 524288 = 1024 segs * 4 h * 128 k
    int o = e + i * 28672;
    if (o < 524288) zws[o] = 0.f;
  }
  if (e >= 24576) {                         // gw2 [4][256] -> 8 sigma-g frags
    int local = e - 24576;                  // 4096
    int j = local & 7, lane = (local >> 3) & 63, s = local >> 9;
    int row = lane & 15, quad = (lane >> 4) & 3;
    int w = s * 32 + ((j >> 2) << 4) + 4 * quad + (j & 3);
    gw2s[local] = (row < 4) ? f2bf(gw2[row * 256 + w]) : (unsigned short)0;
    return;
  }
  const float* src; unsigned short* dst; int local;
  if (e < 16384) { src = gw1; dst = gw1s; local = e; }
  else           { src = mw1; dst = mw1s; local = e - 16384; }
  int j = local & 7, lane = (local >> 3) & 63, tile = local >> 9;
  int ks = tile & 1, mtile = tile >> 1;
  int row = mtile * 16 + (lane & 15);
  int k   = ks * 32 + ((lane >> 4) & 3) * 8 + j;
  dst[local] = f2bf(src[row * 64 + k]);
}

// FLUSH: Z head-rows live in quad 0; es replicas xor-reduced across quads.
#define FLUSH() do {                                                          \
  if (quad == 0) {                                                            \
    _Pragma("unroll") for (int mt_ = 0; mt_ < 8; ++mt_)                       \
      _Pragma("unroll") for (int r_ = 0; r_ < 4; ++r_)                        \
        atomicAdd(&zws[((size_t)cur_seg * 4 + r_) * 128 + mt_ * 16 + lcol],   \
                  acc[mt_][r_]);                                              \
  }                                                                           \
  _Pragma("unroll") for (int mt_ = 0; mt_ < 8; ++mt_)                         \
    acc[mt_] = (floatx4){0.f, 0.f, 0.f, 0.f};                                 \
  { float v_ = es; v_ += __shfl_xor(v_, 16); v_ += __shfl_xor(v_, 32);        \
    if (lane < 4) atomicAdd(&denom[cur_seg * 4 + lane], v_); }                \
  es = 0.f;                                                                   \
} while (0)

// ---------------------------------------------------------------------------
// Fused kernel, NO LDS, NO barrier. Per 32-node granule per wave:
//  1. x -> bf16 frags bx (serves gate-L1 B and mlp1 A).
//  2. gate L1 (64 MFMA) + PReLU(max(v,s*v)) -> sigma-g packed B-frags ->
//     gate L2 as 16 MFMA vs zero-padded gw2s. Heads land on quad-0 rows.
//  3. E-transpose: 40 shuffles (sigma-aligned) -> ev[8]/svb[8] per lane.
//  4. mlp1 operand-swapped (32 MFMA) -> relu+bias -> cvtpk pairs land
//     DIRECTLY in Z-MFMA B-frags zb[8] (sigma node->k permutation, 0 shuffles).
//  5. Run loop: masked-E A-frag (rows=heads), 8 MFMA accumulate Z per segment;
//     denom from the SAME bf16-rounded e (consistent softmax).
// MLP L2 hoisted to finalize (linear => commutes with weighted segment-sum).
// k-permutation sigma(q*8+e) = e<4 ? 4q+e : 16+4q+(e-4) on BOTH A(E) and
// B(r1) sides of the Z-MFMA; sigma-g analogue on the gate-L2 K=256.
// ---------------------------------------------------------------------------
__global__ __launch_bounds__(128, 2) void fused_kernel(
    const float* __restrict__ x, const int* __restrict__ batch,
    const unsigned short* __restrict__ gw1s, const unsigned short* __restrict__ mw1s,
    const unsigned short* __restrict__ gw2s, const float* __restrict__ prelu_a,
    const float* __restrict__ b1, float* __restrict__ denom,
    float* __restrict__ zws) {
  const int t = threadIdx.x;
  const int wave = t >> 6, lane = t & 63;
  const int quad = lane >> 4, lcol = lane & 15;

  const float slope = prelu_a[0];   // 0<slope<1 => prelu(v) = max(v, slope*v)
  const int W = blockIdx.x * 2 + wave;
  const int g0 = (int)(((long long)W * NG) / NWAVES);
  const int g1 = (int)(((long long)(W + 1) * NG) / NWAVES);

  float b1v[8];
#pragma unroll
  for (int mt = 0; mt < 8; ++mt) b1v[mt] = b1[mt * 16 + lcol];  // bias per fcol

  floatx4 acc[8];                       // Z accumulator: [mt] x 4 head-rows
#pragma unroll
  for (int mt = 0; mt < 8; ++mt) acc[mt] = (floatx4){0.f, 0.f, 0.f, 0.f};
  float es = 0.f;
  int fs = g0 * 32; if (fs > NN - 1) fs = NN - 1;
  int cur_seg = batch[fs];

  for (int g = g0; g < g1; ++g) {
    const int base = g * 32;
    int sv[2];
    short8 bx[2][2];
#pragma unroll
    for (int nt = 0; nt < 2; ++nt) {
      int node = base + nt * 16 + lcol;
      sv[nt] = batch[node];
      const float* xp = x + (size_t)node * 64 + quad * 8;
      fv4 v0 = ntload4(xp), v1 = ntload4(xp + 4);
      fv4 v2 = ntload4(xp + 32), v3 = ntload4(xp + 36);
      union { short8 s; unsigned u[4]; } u0, u1;
      u0.u[0] = cvtpk(v0[0], v0[1]); u0.u[1] = cvtpk(v0[2], v0[3]);
      u0.u[2] = cvtpk(v1[0], v1[1]); u0.u[3] = cvtpk(v1[2], v1[3]);
      u1.u[0] = cvtpk(v2[0], v2[1]); u1.u[1] = cvtpk(v2[2], v2[3]);
      u1.u[2] = cvtpk(v3[0], v3[1]); u1.u[3] = cvtpk(v3[2], v3[3]);
      bx[nt][0] = u0.s; bx[nt][1] = u1.s;
    }

    // ---- gate L1 MFMA + PReLU -> sigma-g packed B -> gate L2 MFMA ----
    floatx4 cg0 = {0.f, 0.f, 0.f, 0.f}, cg1 = {0.f, 0.f, 0.f, 0.f};
#pragma unroll
    for (int sst = 0; sst < 8; ++sst) {
      union GB { short8 s; unsigned u[4]; } gb0, gb1;
#pragma unroll
      for (int half = 0; half < 2; ++half) {
        const int mt = sst * 2 + half;
        short8 a0 = *(const short8*)(gw1s + ((size_t)(mt * 2 + 0) * 64 + lane) * 8);
        short8 a1 = *(const short8*)(gw1s + ((size_t)(mt * 2 + 1) * 64 + lane) * 8);
        floatx4 c0 = {0.f, 0.f, 0.f, 0.f};
        c0 = MFMA16(a0, bx[0][0], c0);
        c0 = MFMA16(a1, bx[0][1], c0);
        floatx4 c1 = {0.f, 0.f, 0.f, 0.f};
        c1 = MFMA16(a0, bx[1][0], c1);
        c1 = MFMA16(a1, bx[1][1], c1);
        gb0.u[half * 2 + 0] = cvtpk(fmaxf(c0[0], slope * c0[0]),
                                    fmaxf(c0[1], slope * c0[1]));
        gb0.u[half * 2 + 1] = cvtpk(fmaxf(c0[2], slope * c0[2]),
                                    fmaxf(c0[3], slope * c0[3]));
        gb1.u[half * 2 + 0] = cvtpk(fmaxf(c1[0], slope * c1[0]),
                                    fmaxf(c1[1], slope * c1[1]));
        gb1.u[half * 2 + 1] = cvtpk(fmaxf(c1[2], slope * c1[2]),
                                    fmaxf(c1[3], slope * c1[3]));
      }
      short8 ga = *(const short8*)(gw2s + ((size_t)sst * 64 + lane) * 8);
      cg0 = MFMA16(ga, gb0.s, cg0);
      cg1 = MFMA16(ga, gb1.s, cg1);
    }
    float e0a[4], e1a[4];
#pragma unroll
    for (int hh = 0; hh < 4; ++hh) {
      e0a[hh] = __expf(cg0[hh]);   // |gate| small -> no running max needed
      e1a[hh] = __expf(cg1[hh]);
    }

    // ---- E-transpose (sigma-aligned): ev[e] = e(node=sigma(q*8+e), h=lcol) ----
    float ev[8]; int svb[8];
#pragma unroll
    for (int j = 0; j < 4; ++j) {
      int src = 4 * quad + j;
      svb[j]     = __shfl(sv[0], src);
      svb[4 + j] = __shfl(sv[1], src);
      float t0 = __shfl(e0a[0], src), t1 = __shfl(e0a[1], src);
      float t2 = __shfl(e0a[2], src), t3 = __shfl(e0a[3], src);
      float c01 = (lcol & 1) ? t1 : t0, c23 = (lcol & 1) ? t3 : t2;
      ev[j] = (lcol & 2) ? c23 : c01;
      t0 = __shfl(e1a[0], src); t1 = __shfl(e1a[1], src);
      t2 = __shfl(e1a[2], src); t3 = __shfl(e1a[3], src);
      c01 = (lcol & 1) ? t1 : t0; c23 = (lcol & 1) ? t3 : t2;
      ev[4 + j] = (lcol & 2) ? c23 : c01;
    }

    // ---- mlp1 swapped -> zb[mt] = Z-MFMA B-frags (sigma order, 0 shuffles) --
    union BH { short8 s; unsigned u[4]; } zb[8];
#pragma unroll
    for (int mt = 0; mt < 8; ++mt) {
      short8 w0 = *(const short8*)(mw1s + ((size_t)(mt * 2 + 0) * 64 + lane) * 8);
      short8 w1 = *(const short8*)(mw1s + ((size_t)(mt * 2 + 1) * 64 + lane) * 8);
      float bb = b1v[mt];
      floatx4 c0 = {0.f, 0.f, 0.f, 0.f};
      c0 = MFMA16(bx[0][0], w0, c0);      // A = x (rows=node), B = mw1 (cols=fcol)
      c0 = MFMA16(bx[0][1], w1, c0);
      floatx4 c1 = {0.f, 0.f, 0.f, 0.f};
      c1 = MFMA16(bx[1][0], w0, c1);
      c1 = MFMA16(bx[1][1], w1, c1);
      zb[mt].u[0] = cvtpk(fmaxf(c0[0] + bb, 0.f), fmaxf(c0[1] + bb, 0.f));
      zb[mt].u[1] = cvtpk(fmaxf(c0[2] + bb, 0.f), fmaxf(c0[3] + bb, 0.f));
      zb[mt].u[2] = cvtpk(fmaxf(c1[0] + bb, 0.f), fmaxf(c1[1] + bb, 0.f));
      zb[mt].u[3] = cvtpk(fmaxf(c1[2] + bb, 0.f), fmaxf(c1[3] + bb, 0.f));
    }

    // ---- run loop over segments within the 32 nodes ----
    int p = 0;
    while (p < 32) {
      int selv = (p >> 4) ? sv[1] : sv[0];
      int s = __shfl(selv, p & 15);     // seg of first unprocessed node (uniform)
      if (s != cur_seg) { FLUSH(); cur_seg = s; }
      int cnt = (int)__popcll(__ballot(sv[0] == s)) +
                (int)__popcll(__ballot(sv[1] == s));
      union { unsigned u[4]; short8 s8; } ea;
#pragma unroll
      for (int jj = 0; jj < 4; ++jj) {
        float e0 = (lcol < 4 && svb[2 * jj] == s) ? ev[2 * jj] : 0.f;
        float e1 = (lcol < 4 && svb[2 * jj + 1] == s) ? ev[2 * jj + 1] : 0.f;
        ea.u[jj] = cvtpk(e0, e1);
        es += bflo(ea.u[jj]) + bfhi(ea.u[jj]);   // denom from SAME rounded e
      }
#pragma unroll
      for (int mt = 0; mt < 8; ++mt)
        acc[mt] = MFMA16(ea.s8, zb[mt].s, acc[mt]);
      p += (cnt >> 2);                  // 4 quads replicate each node
    }
  }
  FLUSH();
}

// ---------------------------------------------------------------------------
// Finalize (fp32, exact): out[seg,fcol] = mw2[fcol,:].Z[seg,h(fcol),:]/denom
//                                         + b2[fcol]   (h = fcol>>5)
// ---------------------------------------------------------------------------
__global__ __launch_bounds__(128) void finalize_kernel(
    const float* __restrict__ zws, const float* __restrict__ denom,
    const float* __restrict__ mw2, const float* __restrict__ b2,
    float* __restrict__ out) {
  __shared__ float zL[512];
  const int seg = blockIdx.x, t = threadIdx.x;
#pragma unroll
  for (int i = 0; i < 4; ++i) zL[t + i * 128] = zws[(size_t)seg * 512 + t + i * 128];
  __syncthreads();
  const int fcol = t, h = t >> 5;
  float d = denom[seg * 4 + h];
  const fv4* mrow = (const fv4*)(mw2 + (size_t)fcol * 128);
  const fv4* zrow = (const fv4*)(zL + h * 128);
  float a0 = 0.f, a1 = 0.f, a2 = 0.f, a3 = 0.f;
#pragma unroll 8
  for (int k = 0; k < 32; ++k) {
    fv4 w = mrow[k], z = zrow[k];
    a0 = fmaf(w[0], z[0], a0); a1 = fmaf(w[1], z[1], a1);
    a2 = fmaf(w[2], z[2], a2); a3 = fmaf(w[3], z[3], a3);
  }
  float acc = (a0 + a1) + (a2 + a3);
  out[(size_t)seg * 128 + fcol] = (d > 0.f) ? (acc / d + b2[fcol]) : 0.f;
}

// ---------------------------------------------------------------------------
extern "C" void kernel_launch(void* const* d_in, const int* in_sizes, int n_in,
                              void* d_out, int out_size, void* d_ws, size_t ws_size,
                              hipStream_t stream) {
  const float* x     = (const float*)d_in[0];
  const int*   batch = (const int*)d_in[1];
  // d_in[2] = num_segments (constant 1024, unused)
  const float* gw1 = (const float*)d_in[3];
  const float* pa  = (const float*)d_in[4];
  const float* gw2 = (const float*)d_in[5];
  const float* mw1 = (const float*)d_in[6];
  const float* mb1 = (const float*)d_in[7];
  const float* mw2 = (const float*)d_in[8];
  const float* mb2 = (const float*)d_in[9];
  float* out = (float*)d_out;

  char* ws = (char*)d_ws;
  float* denom = (float*)ws;                              // 16,384 B
  unsigned short* gw1s = (unsigned short*)(ws + 16384);   // 32,768 B
  unsigned short* mw1s = (unsigned short*)(ws + 49152);   // 16,384 B
  unsigned short* gw2s = (unsigned short*)(ws + 65536);   //  8,192 B
  float* zws = (float*)(ws + 73728);                      // 2,097,152 B (Z)

  swizzle_weights<<<112, 256, 0, stream>>>(gw1, mw1, gw2, gw1s, mw1s, gw2s,
                                           denom, zws);

  fused_kernel<<<NBLK, 128, 0, stream>>>(x, batch, gw1s, mw1s, gw2s,
                                         pa, mb1, denom, zws);

  finalize_kernel<<<1024, 128, 0, stream>>>(zws, denom, mw2, mb2, out);
}

// Round 8
// 259.943 us; speedup vs baseline: 1.5910x; 1.0281x over previous
//
#include <hip/hip_runtime.h>
#include <cstdint>
#include <cstddef>

#define NN 500000            // nodes; NN%32==0 -> no tail
#define NG 15625             // 32-node granules
#define NBLK 512             // 256-thread blocks; 2/CU (LDS-bound) -> 8 waves/CU
#define NWAVES (NBLK * 4)
// IN_CH=64, HEADS=4, OUT_CH=32, F=128 mlp hidden, GH=256 gate hidden, SEGS=1024

typedef __attribute__((ext_vector_type(8))) short short8;   // 8 bf16 MFMA frag
typedef __attribute__((ext_vector_type(4))) float floatx4;  // MFMA accumulator
typedef __attribute__((ext_vector_type(4))) float fv4;

__device__ __forceinline__ unsigned short f2bf(float f) {
  union { float f; unsigned u; } v; v.f = f;
  unsigned r = v.u + 0x7FFFu + ((v.u >> 16) & 1u);  // RNE
  return (unsigned short)(r >> 16);
}
__device__ __forceinline__ unsigned cvtpk(float a, float b) {
  unsigned r;
  asm("v_cvt_pk_bf16_f32 %0, %1, %2" : "=v"(r) : "v"(a), "v"(b));
  return r;
}
__device__ __forceinline__ float bflo(unsigned u) {  // low bf16 -> f32
  union { unsigned u; float f; } v; v.u = u << 16; return v.f;
}
__device__ __forceinline__ float bfhi(unsigned u) {  // high bf16 -> f32
  union { unsigned u; float f; } v; v.u = u & 0xffff0000u; return v.f;
}

#define MFMA16(a, b, c) __builtin_amdgcn_mfma_f32_16x16x32_bf16((a), (b), (c), 0, 0, 0)

// FLUSH: Z head-rows live in quad 0; es replicas xor-reduced across quads.
#define FLUSH() do {                                                          \
  if (quad == 0) {                                                            \
    _Pragma("unroll") for (int mt_ = 0; mt_ < 8; ++mt_)                       \
      _Pragma("unroll") for (int r_ = 0; r_ < 4; ++r_)                        \
        atomicAdd(&zws[((size_t)cur_seg * 4 + r_) * 128 + mt_ * 16 + lcol],   \
                  acc[mt_][r_]);                                              \
  }                                                                           \
  _Pragma("unroll") for (int mt_ = 0; mt_ < 8; ++mt_)                         \
    acc[mt_] = (floatx4){0.f, 0.f, 0.f, 0.f};                                 \
  { float v_ = es; v_ += __shfl_xor(v_, 16); v_ += __shfl_xor(v_, 32);        \
    if (lane < 4) atomicAdd(&denom[cur_seg * 4 + lane], v_); }                \
  es = 0.f;                                                                   \
} while (0)

// ---------------------------------------------------------------------------
// Fused kernel. 256-thread blocks; the ENTIRE swizzled weight set (56 KB:
// gw1s 32K | mw1s 16K | gw2s 8K bf16 fragments) is built fp32->bf16 directly
// into LDS in the prologue (one barrier) and shared by the block's 4 waves.
// Rationale (R7 counters): per-granule 56 weight-fragment loads from L2 were
// the dominant stall (both pipes <25%, 60% idle); ds_read_b128 with immediate
// offsets removes that latency AND ~170 VALU/granule of 64-bit address math.
// x loads are now cacheable (no NT hint): 128 MB x fits L3 across dispatches.
// Per 32-node granule per wave (all register-resident, sigma-permuted k):
//  gate L1 (64 MFMA) + PReLU -> sigma-g packed B -> gate L2 (16 MFMA);
//  E-transpose 40 shuffles; mlp1 swapped (32 MFMA) -> zb B-frags (0 shuffles);
//  run loop: masked-E A-frag, 8 MFMA accumulate Z per segment; denom from the
//  SAME bf16-rounded e. MLP L2 hoisted to finalize (linear <-> segment-sum).
// ---------------------------------------------------------------------------
__global__ __launch_bounds__(256, 2) void fused_kernel(
    const float* __restrict__ x, const int* __restrict__ batch,
    const float* __restrict__ gw1, const float* __restrict__ mw1,
    const float* __restrict__ gw2, const float* __restrict__ prelu_a,
    const float* __restrict__ b1, float* __restrict__ denom,
    float* __restrict__ zws) {
  __shared__ unsigned short wl[28672];   // 56 KB
  const int t = threadIdx.x;

  // ---- prologue: swizzle fp32 weights -> bf16 MFMA fragments in LDS ----
  // gw1s/mw1s: frag f=(mtile*2+ks), element (lane,j) = W[mtile*16+(lane&15)]
  //            [ks*32+((lane>>4)&3)*8+j].  gw2s: sigma-g A-frags, rows 4-15=0.
#pragma unroll 4
  for (int e = t; e < 28672; e += 256) {
    unsigned short v;
    if (e < 24576) {
      const float* src = (e < 16384) ? gw1 : mw1;
      int local = (e < 16384) ? e : e - 16384;
      int j = local & 7, lane = (local >> 3) & 63, tile = local >> 9;
      int row = (tile >> 1) * 16 + (lane & 15);
      int k = (tile & 1) * 32 + ((lane >> 4) & 3) * 8 + j;
      v = f2bf(src[row * 64 + k]);
    } else {
      int local = e - 24576;
      int j = local & 7, lane = (local >> 3) & 63, s = local >> 9;
      int row = lane & 15, q = (lane >> 4) & 3;
      int w = s * 32 + ((j >> 2) << 4) + 4 * q + (j & 3);
      v = (row < 4) ? f2bf(gw2[row * 256 + w]) : (unsigned short)0;
    }
    wl[e] = v;
  }
  __syncthreads();   // only barrier in the kernel
  const unsigned short* gw1s = wl;
  const unsigned short* mw1s = wl + 16384;
  const unsigned short* gw2s = wl + 24576;

  const int wave = t >> 6, lane = t & 63;
  const int quad = lane >> 4, lcol = lane & 15;
  const float slope = prelu_a[0];   // 0<slope<1 => prelu(v) = max(v, slope*v)
  const int W = blockIdx.x * 4 + wave;
  const int g0 = (int)(((long long)W * NG) / NWAVES);
  const int g1 = (int)(((long long)(W + 1) * NG) / NWAVES);

  float b1v[8];
#pragma unroll
  for (int mt = 0; mt < 8; ++mt) b1v[mt] = b1[mt * 16 + lcol];  // bias per fcol

  floatx4 acc[8];                       // Z accumulator: [mt] x 4 head-rows
#pragma unroll
  for (int mt = 0; mt < 8; ++mt) acc[mt] = (floatx4){0.f, 0.f, 0.f, 0.f};
  float es = 0.f;
  int fs = g0 * 32; if (fs > NN - 1) fs = NN - 1;
  int cur_seg = batch[fs];

  for (int g = g0; g < g1; ++g) {
    const int base = g * 32;
    int sv[2];
    short8 bx[2][2];
#pragma unroll
    for (int nt = 0; nt < 2; ++nt) {
      int node = base + nt * 16 + lcol;
      sv[nt] = batch[node];
      const float* xp = x + (size_t)node * 64 + quad * 8;
      fv4 v0 = *(const fv4*)xp,        v1 = *(const fv4*)(xp + 4);
      fv4 v2 = *(const fv4*)(xp + 32), v3 = *(const fv4*)(xp + 36);
      union { short8 s; unsigned u[4]; } u0, u1;
      u0.u[0] = cvtpk(v0[0], v0[1]); u0.u[1] = cvtpk(v0[2], v0[3]);
      u0.u[2] = cvtpk(v1[0], v1[1]); u0.u[3] = cvtpk(v1[2], v1[3]);
      u1.u[0] = cvtpk(v2[0], v2[1]); u1.u[1] = cvtpk(v2[2], v2[3]);
      u1.u[2] = cvtpk(v3[0], v3[1]); u1.u[3] = cvtpk(v3[2], v3[3]);
      bx[nt][0] = u0.s; bx[nt][1] = u1.s;
    }

    // ---- gate L1 MFMA + PReLU -> sigma-g packed B -> gate L2 MFMA ----
    floatx4 cg0 = {0.f, 0.f, 0.f, 0.f}, cg1 = {0.f, 0.f, 0.f, 0.f};
#pragma unroll
    for (int sst = 0; sst < 8; ++sst) {
      union GB { short8 s; unsigned u[4]; } gb0, gb1;
#pragma unroll
      for (int half = 0; half < 2; ++half) {
        const int mt = sst * 2 + half;
        short8 a0 = *(const short8*)(gw1s + ((size_t)(mt * 2 + 0) * 64 + lane) * 8);
        short8 a1 = *(const short8*)(gw1s + ((size_t)(mt * 2 + 1) * 64 + lane) * 8);
        floatx4 c0 = {0.f, 0.f, 0.f, 0.f};
        c0 = MFMA16(a0, bx[0][0], c0);
        c0 = MFMA16(a1, bx[0][1], c0);
        floatx4 c1 = {0.f, 0.f, 0.f, 0.f};
        c1 = MFMA16(a0, bx[1][0], c1);
        c1 = MFMA16(a1, bx[1][1], c1);
        gb0.u[half * 2 + 0] = cvtpk(fmaxf(c0[0], slope * c0[0]),
                                    fmaxf(c0[1], slope * c0[1]));
        gb0.u[half * 2 + 1] = cvtpk(fmaxf(c0[2], slope * c0[2]),
                                    fmaxf(c0[3], slope * c0[3]));
        gb1.u[half * 2 + 0] = cvtpk(fmaxf(c1[0], slope * c1[0]),
                                    fmaxf(c1[1], slope * c1[1]));
        gb1.u[half * 2 + 1] = cvtpk(fmaxf(c1[2], slope * c1[2]),
                                    fmaxf(c1[3], slope * c1[3]));
      }
      short8 ga = *(const short8*)(gw2s + ((size_t)sst * 64 + lane) * 8);
      cg0 = MFMA16(ga, gb0.s, cg0);
      cg1 = MFMA16(ga, gb1.s, cg1);
    }
    float e0a[4], e1a[4];
#pragma unroll
    for (int hh = 0; hh < 4; ++hh) {
      e0a[hh] = __expf(cg0[hh]);   // |gate| small -> no running max needed
      e1a[hh] = __expf(cg1[hh]);
    }

    // ---- E-transpose (sigma-aligned): ev[e] = e(node=sigma(q*8+e), h=lcol) ----
    float ev[8]; int svb[8];
#pragma unroll
    for (int j = 0; j < 4; ++j) {
      int src = 4 * quad + j;
      svb[j]     = __shfl(sv[0], src);
      svb[4 + j] = __shfl(sv[1], src);
      float t0 = __shfl(e0a[0], src), t1 = __shfl(e0a[1], src);
      float t2 = __shfl(e0a[2], src), t3 = __shfl(e0a[3], src);
      float c01 = (lcol & 1) ? t1 : t0, c23 = (lcol & 1) ? t3 : t2;
      ev[j] = (lcol & 2) ? c23 : c01;
      t0 = __shfl(e1a[0], src); t1 = __shfl(e1a[1], src);
      t2 = __shfl(e1a[2], src); t3 = __shfl(e1a[3], src);
      c01 = (lcol & 1) ? t1 : t0; c23 = (lcol & 1) ? t3 : t2;
      ev[4 + j] = (lcol & 2) ? c23 : c01;
    }

    // ---- mlp1 swapped -> zb[mt] = Z-MFMA B-frags (sigma order, 0 shuffles) --
    union BH { short8 s; unsigned u[4]; } zb[8];
#pragma unroll
    for (int mt = 0; mt < 8; ++mt) {
      short8 w0 = *(const short8*)(mw1s + ((size_t)(mt * 2 + 0) * 64 + lane) * 8);
      short8 w1 = *(const short8*)(mw1s + ((size_t)(mt * 2 + 1) * 64 + lane) * 8);
      float bb = b1v[mt];
      floatx4 c0 = {0.f, 0.f, 0.f, 0.f};
      c0 = MFMA16(bx[0][0], w0, c0);      // A = x (rows=node), B = mw1 (cols=fcol)
      c0 = MFMA16(bx[0][1], w1, c0);
      floatx4 c1 = {0.f, 0.f, 0.f, 0.f};
      c1 = MFMA16(bx[1][0], w0, c1);
      c1 = MFMA16(bx[1][1], w1, c1);
      zb[mt].u[0] = cvtpk(fmaxf(c0[0] + bb, 0.f), fmaxf(c0[1] + bb, 0.f));
      zb[mt].u[1] = cvtpk(fmaxf(c0[2] + bb, 0.f), fmaxf(c0[3] + bb, 0.f));
      zb[mt].u[2] = cvtpk(fmaxf(c1[0] + bb, 0.f), fmaxf(c1[1] + bb, 0.f));
      zb[mt].u[3] = cvtpk(fmaxf(c1[2] + bb, 0.f), fmaxf(c1[3] + bb, 0.f));
    }

    // ---- run loop over segments within the 32 nodes ----
    int p = 0;
    while (p < 32) {
      int selv = (p >> 4) ? sv[1] : sv[0];
      int s = __shfl(selv, p & 15);     // seg of first unprocessed node (uniform)
      if (s != cur_seg) { FLUSH(); cur_seg = s; }
      int cnt = (int)__popcll(__ballot(sv[0] == s)) +
                (int)__popcll(__ballot(sv[1] == s));
      union { unsigned u[4]; short8 s8; } ea;
#pragma unroll
      for (int jj = 0; jj < 4; ++jj) {
        float e0 = (lcol < 4 && svb[2 * jj] == s) ? ev[2 * jj] : 0.f;
        float e1 = (lcol < 4 && svb[2 * jj + 1] == s) ? ev[2 * jj + 1] : 0.f;
        ea.u[jj] = cvtpk(e0, e1);
        es += bflo(ea.u[jj]) + bfhi(ea.u[jj]);   // denom from SAME rounded e
      }
#pragma unroll
      for (int mt = 0; mt < 8; ++mt)
        acc[mt] = MFMA16(ea.s8, zb[mt].s, acc[mt]);
      p += (cnt >> 2);                  // 4 quads replicate each node
    }
  }
  FLUSH();
}

// ---------------------------------------------------------------------------
// Finalize (fp32, exact): out[seg,fcol] = mw2[fcol,:].Z[seg,h(fcol),:]/denom
//                                         + b2[fcol]   (h = fcol>>5)
// ---------------------------------------------------------------------------
__global__ __launch_bounds__(128) void finalize_kernel(
    const float* __restrict__ zws, const float* __restrict__ denom,
    const float* __restrict__ mw2, const float* __restrict__ b2,
    float* __restrict__ out) {
  __shared__ float zL[512];
  const int seg = blockIdx.x, t = threadIdx.x;
#pragma unroll
  for (int i = 0; i < 4; ++i) zL[t + i * 128] = zws[(size_t)seg * 512 + t + i * 128];
  __syncthreads();
  const int fcol = t, h = t >> 5;
  float d = denom[seg * 4 + h];
  const fv4* mrow = (const fv4*)(mw2 + (size_t)fcol * 128);
  const fv4* zrow = (const fv4*)(zL + h * 128);
  float a0 = 0.f, a1 = 0.f, a2 = 0.f, a3 = 0.f;
#pragma unroll 8
  for (int k = 0; k < 32; ++k) {
    fv4 w = mrow[k], z = zrow[k];
    a0 = fmaf(w[0], z[0], a0); a1 = fmaf(w[1], z[1], a1);
    a2 = fmaf(w[2], z[2], a2); a3 = fmaf(w[3], z[3], a3);
  }
  float acc = (a0 + a1) + (a2 + a3);
  out[(size_t)seg * 128 + fcol] = (d > 0.f) ? (acc / d + b2[fcol]) : 0.f;
}

// ---------------------------------------------------------------------------
extern "C" void kernel_launch(void* const* d_in, const int* in_sizes, int n_in,
                              void* d_out, int out_size, void* d_ws, size_t ws_size,
                              hipStream_t stream) {
  const float* x     = (const float*)d_in[0];
  const int*   batch = (const int*)d_in[1];
  // d_in[2] = num_segments (constant 1024, unused)
  const float* gw1 = (const float*)d_in[3];
  const float* pa  = (const float*)d_in[4];
  const float* gw2 = (const float*)d_in[5];
  const float* mw1 = (const float*)d_in[6];
  const float* mb1 = (const float*)d_in[7];
  const float* mw2 = (const float*)d_in[8];
  const float* mb2 = (const float*)d_in[9];
  float* out = (float*)d_out;

  char* ws = (char*)d_ws;
  float* denom = (float*)ws;                              // 16,384 B
  float* zws   = (float*)(ws + 16384);                    // 2,097,152 B (Z)

  hipMemsetAsync(denom, 0, 16384, stream);
  hipMemsetAsync(zws, 0, 2097152, stream);

  fused_kernel<<<NBLK, 256, 0, stream>>>(x, batch, gw1, mw1, gw2,
                                         pa, mb1, denom, zws);

  finalize_kernel<<<1024, 128, 0, stream>>>(zws, denom, mw2, mb2, out);
}

// Round 9
// 257.264 us; speedup vs baseline: 1.6075x; 1.0104x over previous
//
#include <hip/hip_runtime.h>
#include <cstdint>
#include <cstddef>

#define NN 500000            // nodes; NN%32==0 -> no tail
#define NG 15625             // 32-node granules
#define NBLK 768             // 256-thread blocks; 3/CU (48KB LDS) -> 12 waves/CU
#define NWAVES (NBLK * 4)
// IN_CH=64, HEADS=4, OUT_CH=32, F=128 mlp hidden, GH=256 gate hidden, SEGS=1024

typedef __attribute__((ext_vector_type(8))) short short8;   // 8 bf16 MFMA frag
typedef __attribute__((ext_vector_type(4))) float floatx4;  // MFMA accumulator
typedef __attribute__((ext_vector_type(4))) float fv4;

__device__ __forceinline__ unsigned short f2bf(float f) {
  union { float f; unsigned u; } v; v.f = f;
  unsigned r = v.u + 0x7FFFu + ((v.u >> 16) & 1u);  // RNE
  return (unsigned short)(r >> 16);
}
__device__ __forceinline__ unsigned cvtpk(float a, float b) {
  unsigned r;
  asm("v_cvt_pk_bf16_f32 %0, %1, %2" : "=v"(r) : "v"(a), "v"(b));
  return r;
}
__device__ __forceinline__ float bflo(unsigned u) {  // low bf16 -> f32
  union { unsigned u; float f; } v; v.u = u << 16; return v.f;
}
__device__ __forceinline__ float bfhi(unsigned u) {  // high bf16 -> f32
  union { unsigned u; float f; } v; v.u = u & 0xffff0000u; return v.f;
}

#define MFMA16(a, b, c) __builtin_amdgcn_mfma_f32_16x16x32_bf16((a), (b), (c), 0, 0, 0)

// FLUSH: Z head-rows live in quad 0; es replicas xor-reduced across quads.
#define FLUSH() do {                                                          \
  if (quad == 0) {                                                            \
    _Pragma("unroll") for (int mt_ = 0; mt_ < 8; ++mt_)                       \
      _Pragma("unroll") for (int r_ = 0; r_ < 4; ++r_)                        \
        atomicAdd(&zws[((size_t)cur_seg * 4 + r_) * 128 + mt_ * 16 + lcol],   \
                  acc[mt_][r_]);                                              \
  }                                                                           \
  _Pragma("unroll") for (int mt_ = 0; mt_ < 8; ++mt_)                         \
    acc[mt_] = (floatx4){0.f, 0.f, 0.f, 0.f};                                 \
  { float v_ = es; v_ += __shfl_xor(v_, 16); v_ += __shfl_xor(v_, 32);        \
    if (lane < 4) atomicAdd(&denom[cur_seg * 4 + lane], v_); }                \
  es = 0.f;                                                                   \
} while (0)

// Prefetch next granule's batch + x into registers (consumed next iteration).
#define PREF(gg) do {                                                         \
  _Pragma("unroll") for (int nt_ = 0; nt_ < 2; ++nt_) {                       \
    int node_ = (gg) * 32 + nt_ * 16 + lcol;                                  \
    svp[nt_] = batch[node_];                                                  \
    const float* xp_ = x + (size_t)node_ * 64 + quad * 8;                     \
    xq[nt_][0] = *(const fv4*)xp_;        xq[nt_][1] = *(const fv4*)(xp_ + 4);\
    xq[nt_][2] = *(const fv4*)(xp_ + 32); xq[nt_][3] = *(const fv4*)(xp_ + 36);\
  } } while (0)

// ---------------------------------------------------------------------------
// Fused kernel. 256-thread blocks; gw1/mw1 bf16 fragments (48 KB) built into
// LDS once per block (one barrier) and shared by 4 waves; gw2 sigma-g
// A-fragments live in 32 REGISTERS/lane (saves 8KB LDS -> 3 blocks/CU).
// Cross-granule software pipeline (R8 lesson: x-load latency was serial-
// exposed at granule top): next granule's batch+x are loaded into registers
// right after the current granule's pack, ~2000 cycles before consumption.
// Per 32-node granule per wave (all register-resident, sigma-permuted k):
//  gate L1 (64 MFMA) + PReLU -> sigma-g packed B -> gate L2 (16 MFMA);
//  E-transpose 40 shuffles; mlp1 swapped (32 MFMA) -> zb B-frags (0 shuffles);
//  run loop: masked-E A-frag, 8 MFMA accumulate Z per segment; denom from the
//  SAME bf16-rounded e. MLP L2 hoisted to finalize (linear <-> segment-sum).
// ---------------------------------------------------------------------------
__global__ __launch_bounds__(256, 2) void fused_kernel(
    const float* __restrict__ x, const int* __restrict__ batch,
    const float* __restrict__ gw1, const float* __restrict__ mw1,
    const float* __restrict__ gw2, const float* __restrict__ prelu_a,
    const float* __restrict__ b1, float* __restrict__ denom,
    float* __restrict__ zws) {
  __shared__ unsigned short wl[24576];   // 48 KB: gw1s 32K | mw1s 16K
  const int t = threadIdx.x;

  // ---- prologue: swizzle fp32 weights -> bf16 MFMA fragments in LDS ----
#pragma unroll 4
  for (int e = t; e < 24576; e += 256) {
    const float* src = (e < 16384) ? gw1 : mw1;
    int local = (e < 16384) ? e : e - 16384;
    int j = local & 7, lane = (local >> 3) & 63, tile = local >> 9;
    int row = (tile >> 1) * 16 + (lane & 15);
    int k = (tile & 1) * 32 + ((lane >> 4) & 3) * 8 + j;
    wl[e] = f2bf(src[row * 64 + k]);
  }
  __syncthreads();   // only barrier in the kernel
  const unsigned short* gw1s = wl;
  const unsigned short* mw1s = wl + 16384;

  const int wave = t >> 6, lane = t & 63;
  const int quad = lane >> 4, lcol = lane & 15;
  const float slope = prelu_a[0];   // 0<slope<1 => prelu(v) = max(v, slope*v)
  const int W = blockIdx.x * 4 + wave;
  const int g0 = (int)(((long long)W * NG) / NWAVES);
  const int g1 = (int)(((long long)(W + 1) * NG) / NWAVES);

  // gw2 sigma-g A-fragments in registers (rows 4-15 of the 16-row tile = 0).
  short8 gareg[8];
#pragma unroll
  for (int sst = 0; sst < 8; ++sst) {
    union { short8 s; unsigned short h[8]; } u;
#pragma unroll
    for (int j = 0; j < 8; ++j) {
      int w = sst * 32 + ((j >> 2) << 4) + 4 * quad + (j & 3);
      u.h[j] = (lcol < 4) ? f2bf(gw2[lcol * 256 + w]) : (unsigned short)0;
    }
    gareg[sst] = u.s;
  }

  float b1v[8];
#pragma unroll
  for (int mt = 0; mt < 8; ++mt) b1v[mt] = b1[mt * 16 + lcol];  // bias per fcol

  floatx4 acc[8];                       // Z accumulator: [mt] x 4 head-rows
#pragma unroll
  for (int mt = 0; mt < 8; ++mt) acc[mt] = (floatx4){0.f, 0.f, 0.f, 0.f};
  float es = 0.f;
  int fs = g0 * 32; if (fs > NN - 1) fs = NN - 1;
  int cur_seg = batch[fs];

  int svp[2]; fv4 xq[2][4];
  PREF(g0);

  for (int g = g0; g < g1; ++g) {
    int sv[2] = {svp[0], svp[1]};
    short8 bx[2][2];
#pragma unroll
    for (int nt = 0; nt < 2; ++nt) {    // pack prefetched x -> bf16 frags
      union { short8 s; unsigned u[4]; } u0, u1;
      u0.u[0] = cvtpk(xq[nt][0][0], xq[nt][0][1]);
      u0.u[1] = cvtpk(xq[nt][0][2], xq[nt][0][3]);
      u0.u[2] = cvtpk(xq[nt][1][0], xq[nt][1][1]);
      u0.u[3] = cvtpk(xq[nt][1][2], xq[nt][1][3]);
      u1.u[0] = cvtpk(xq[nt][2][0], xq[nt][2][1]);
      u1.u[1] = cvtpk(xq[nt][2][2], xq[nt][2][3]);
      u1.u[2] = cvtpk(xq[nt][3][0], xq[nt][3][1]);
      u1.u[3] = cvtpk(xq[nt][3][2], xq[nt][3][3]);
      bx[nt][0] = u0.s; bx[nt][1] = u1.s;
    }
    {  // issue next granule's loads NOW; latency hides under this granule
      int gn = (g + 1 < NG) ? (g + 1) : g;
      PREF(gn);
    }

    // ---- gate L1 MFMA + PReLU -> sigma-g packed B -> gate L2 MFMA ----
    floatx4 cg0 = {0.f, 0.f, 0.f, 0.f}, cg1 = {0.f, 0.f, 0.f, 0.f};
#pragma unroll
    for (int sst = 0; sst < 8; ++sst) {
      union GB { short8 s; unsigned u[4]; } gb0, gb1;
#pragma unroll
      for (int half = 0; half < 2; ++half) {
        const int mt = sst * 2 + half;
        short8 a0 = *(const short8*)(gw1s + ((size_t)(mt * 2 + 0) * 64 + lane) * 8);
        short8 a1 = *(const short8*)(gw1s + ((size_t)(mt * 2 + 1) * 64 + lane) * 8);
        floatx4 c0 = {0.f, 0.f, 0.f, 0.f};
        c0 = MFMA16(a0, bx[0][0], c0);
        c0 = MFMA16(a1, bx[0][1], c0);
        floatx4 c1 = {0.f, 0.f, 0.f, 0.f};
        c1 = MFMA16(a0, bx[1][0], c1);
        c1 = MFMA16(a1, bx[1][1], c1);
        gb0.u[half * 2 + 0] = cvtpk(fmaxf(c0[0], slope * c0[0]),
                                    fmaxf(c0[1], slope * c0[1]));
        gb0.u[half * 2 + 1] = cvtpk(fmaxf(c0[2], slope * c0[2]),
                                    fmaxf(c0[3], slope * c0[3]));
        gb1.u[half * 2 + 0] = cvtpk(fmaxf(c1[0], slope * c1[0]),
                                    fmaxf(c1[1], slope * c1[1]));
        gb1.u[half * 2 + 1] = cvtpk(fmaxf(c1[2], slope * c1[2]),
                                    fmaxf(c1[3], slope * c1[3]));
      }
      cg0 = MFMA16(gareg[sst], gb0.s, cg0);
      cg1 = MFMA16(gareg[sst], gb1.s, cg1);
    }
    float e0a[4], e1a[4];
#pragma unroll
    for (int hh = 0; hh < 4; ++hh) {
      e0a[hh] = __expf(cg0[hh]);   // |gate| small -> no running max needed
      e1a[hh] = __expf(cg1[hh]);
    }

    // ---- E-transpose (sigma-aligned): ev[e] = e(node=sigma(q*8+e), h=lcol) ----
    float ev[8]; int svb[8];
#pragma unroll
    for (int j = 0; j < 4; ++j) {
      int src = 4 * quad + j;
      svb[j]     = __shfl(sv[0], src);
      svb[4 + j] = __shfl(sv[1], src);
      float t0 = __shfl(e0a[0], src), t1 = __shfl(e0a[1], src);
      float t2 = __shfl(e0a[2], src), t3 = __shfl(e0a[3], src);
      float c01 = (lcol & 1) ? t1 : t0, c23 = (lcol & 1) ? t3 : t2;
      ev[j] = (lcol & 2) ? c23 : c01;
      t0 = __shfl(e1a[0], src); t1 = __shfl(e1a[1], src);
      t2 = __shfl(e1a[2], src); t3 = __shfl(e1a[3], src);
      c01 = (lcol & 1) ? t1 : t0; c23 = (lcol & 1) ? t3 : t2;
      ev[4 + j] = (lcol & 2) ? c23 : c01;
    }

    // ---- mlp1 swapped -> zb[mt] = Z-MFMA B-frags (sigma order, 0 shuffles) --
    union BH { short8 s; unsigned u[4]; } zb[8];
#pragma unroll
    for (int mt = 0; mt < 8; ++mt) {
      short8 w0 = *(const short8*)(mw1s + ((size_t)(mt * 2 + 0) * 64 + lane) * 8);
      short8 w1 = *(const short8*)(mw1s + ((size_t)(mt * 2 + 1) * 64 + lane) * 8);
      float bb = b1v[mt];
      floatx4 c0 = {0.f, 0.f, 0.f, 0.f};
      c0 = MFMA16(bx[0][0], w0, c0);      // A = x (rows=node), B = mw1 (cols=fcol)
      c0 = MFMA16(bx[0][1], w1, c0);
      floatx4 c1 = {0.f, 0.f, 0.f, 0.f};
      c1 = MFMA16(bx[1][0], w0, c1);
      c1 = MFMA16(bx[1][1], w1, c1);
      zb[mt].u[0] = cvtpk(fmaxf(c0[0] + bb, 0.f), fmaxf(c0[1] + bb, 0.f));
      zb[mt].u[1] = cvtpk(fmaxf(c0[2] + bb, 0.f), fmaxf(c0[3] + bb, 0.f));
      zb[mt].u[2] = cvtpk(fmaxf(c1[0] + bb, 0.f), fmaxf(c1[1] + bb, 0.f));
      zb[mt].u[3] = cvtpk(fmaxf(c1[2] + bb, 0.f), fmaxf(c1[3] + bb, 0.f));
    }

    // ---- run loop over segments within the 32 nodes ----
    int p = 0;
    while (p < 32) {
      int selv = (p >> 4) ? sv[1] : sv[0];
      int s = __shfl(selv, p & 15);     // seg of first unprocessed node (uniform)
      if (s != cur_seg) { FLUSH(); cur_seg = s; }
      int cnt = (int)__popcll(__ballot(sv[0] == s)) +
                (int)__popcll(__ballot(sv[1] == s));
      union { unsigned u[4]; short8 s8; } ea;
#pragma unroll
      for (int jj = 0; jj < 4; ++jj) {
        float e0 = (lcol < 4 && svb[2 * jj] == s) ? ev[2 * jj] : 0.f;
        float e1 = (lcol < 4 && svb[2 * jj + 1] == s) ? ev[2 * jj + 1] : 0.f;
        ea.u[jj] = cvtpk(e0, e1);
        es += bflo(ea.u[jj]) + bfhi(ea.u[jj]);   // denom from SAME rounded e
      }
#pragma unroll
      for (int mt = 0; mt < 8; ++mt)
        acc[mt] = MFMA16(ea.s8, zb[mt].s, acc[mt]);
      p += (cnt >> 2);                  // 4 quads replicate each node
    }
  }
  FLUSH();
}

// ---------------------------------------------------------------------------
// Finalize (fp32, exact): out[seg,fcol] = mw2[fcol,:].Z[seg,h(fcol),:]/denom
//                                         + b2[fcol]   (h = fcol>>5)
// ---------------------------------------------------------------------------
__global__ __launch_bounds__(128) void finalize_kernel(
    const float* __restrict__ zws, const float* __restrict__ denom,
    const float* __restrict__ mw2, const float* __restrict__ b2,
    float* __restrict__ out) {
  __shared__ float zL[512];
  const int seg = blockIdx.x, t = threadIdx.x;
#pragma unroll
  for (int i = 0; i < 4; ++i) zL[t + i * 128] = zws[(size_t)seg * 512 + t + i * 128];
  __syncthreads();
  const int fcol = t, h = t >> 5;
  float d = denom[seg * 4 + h];
  const fv4* mrow = (const fv4*)(mw2 + (size_t)fcol * 128);
  const fv4* zrow = (const fv4*)(zL + h * 128);
  float a0 = 0.f, a1 = 0.f, a2 = 0.f, a3 = 0.f;
#pragma unroll 8
  for (int k = 0; k < 32; ++k) {
    fv4 w = mrow[k], z = zrow[k];
    a0 = fmaf(w[0], z[0], a0); a1 = fmaf(w[1], z[1], a1);
    a2 = fmaf(w[2], z[2], a2); a3 = fmaf(w[3], z[3], a3);
  }
  float acc = (a0 + a1) + (a2 + a3);
  out[(size_t)seg * 128 + fcol] = (d > 0.f) ? (acc / d + b2[fcol]) : 0.f;
}

// ---------------------------------------------------------------------------
extern "C" void kernel_launch(void* const* d_in, const int* in_sizes, int n_in,
                              void* d_out, int out_size, void* d_ws, size_t ws_size,
                              hipStream_t stream) {
  const float* x     = (const float*)d_in[0];
  const int*   batch = (const int*)d_in[1];
  // d_in[2] = num_segments (constant 1024, unused)
  const float* gw1 = (const float*)d_in[3];
  const float* pa  = (const float*)d_in[4];
  const float* gw2 = (const float*)d_in[5];
  const float* mw1 = (const float*)d_in[6];
  const float* mb1 = (const float*)d_in[7];
  const float* mw2 = (const float*)d_in[8];
  const float* mb2 = (const float*)d_in[9];
  float* out = (float*)d_out;

  char* ws = (char*)d_ws;
  float* denom = (float*)ws;                              // 16,384 B
  float* zws   = (float*)(ws + 16384);                    // 2,097,152 B (Z)

  hipMemsetAsync(denom, 0, 16384, stream);
  hipMemsetAsync(zws, 0, 2097152, stream);

  fused_kernel<<<NBLK, 256, 0, stream>>>(x, batch, gw1, mw1, gw2,
                                         pa, mb1, denom, zws);

  finalize_kernel<<<1024, 128, 0, stream>>>(zws, denom, mw2, mb2, out);
}

// Round 11
// 254.560 us; speedup vs baseline: 1.6246x; 1.0106x over previous
//
#include <hip/hip_runtime.h>
#include <cstdint>
#include <cstddef>

#define NN 500000            // nodes; NN%32==0 -> no tail
#define NG 15625             // 32-node granules
#define NBLK 768             // 256-thread blocks; 3/CU (48KB LDS) -> 12 waves/CU
#define NWAVES (NBLK * 4)
// IN_CH=64, HEADS=4, OUT_CH=32, F=128 mlp hidden, GH=256 gate hidden, SEGS=1024

typedef __attribute__((ext_vector_type(8))) short short8;   // 8 bf16 MFMA frag
typedef __attribute__((ext_vector_type(4))) float floatx4;  // MFMA accumulator
typedef __attribute__((ext_vector_type(4))) float fv4;

__device__ __forceinline__ unsigned short f2bf(float f) {
  union { float f; unsigned u; } v; v.f = f;
  unsigned r = v.u + 0x7FFFu + ((v.u >> 16) & 1u);  // RNE
  return (unsigned short)(r >> 16);
}
__device__ __forceinline__ unsigned cvtpk(float a, float b) {
  unsigned r;
  asm("v_cvt_pk_bf16_f32 %0, %1, %2" : "=v"(r) : "v"(a), "v"(b));
  return r;
}
__device__ __forceinline__ float bflo(unsigned u) {  // low bf16 -> f32
  union { unsigned u; float f; } v; v.u = u << 16; return v.f;
}
__device__ __forceinline__ float bfhi(unsigned u) {  // high bf16 -> f32
  union { unsigned u; float f; } v; v.u = u & 0xffff0000u; return v.f;
}

#define MFMA16(a, b, c) __builtin_amdgcn_mfma_f32_16x16x32_bf16((a), (b), (c), 0, 0, 0)

// FLUSH: Z head-rows live in quad 0; es replicas xor-reduced across quads.
#define FLUSH() do {                                                          \
  if (quad == 0) {                                                            \
    _Pragma("unroll") for (int mt_ = 0; mt_ < 8; ++mt_)                       \
      _Pragma("unroll") for (int r_ = 0; r_ < 4; ++r_)                        \
        atomicAdd(&zws[((size_t)cur_seg * 4 + r_) * 128 + mt_ * 16 + lcol],   \
                  acc[mt_][r_]);                                              \
  }                                                                           \
  _Pragma("unroll") for (int mt_ = 0; mt_ < 8; ++mt_)                         \
    acc[mt_] = (floatx4){0.f, 0.f, 0.f, 0.f};                                 \
  { float v_ = es; v_ += __shfl_xor(v_, 16); v_ += __shfl_xor(v_, 32);        \
    if (lane < 4) atomicAdd(&denom[cur_seg * 4 + lane], v_); }                \
  es = 0.f;                                                                   \
} while (0)

// Prefetch next granule's batch + x into registers (consumed next iteration).
#define PREF(gg) do {                                                         \
  _Pragma("unroll") for (int nt_ = 0; nt_ < 2; ++nt_) {                       \
    int node_ = (gg) * 32 + nt_ * 16 + lcol;                                  \
    svp[nt_] = batch[node_];                                                  \
    const float* xp_ = x + (size_t)node_ * 64 + quad * 8;                     \
    xq[nt_][0] = *(const fv4*)xp_;        xq[nt_][1] = *(const fv4*)(xp_ + 4);\
    xq[nt_][2] = *(const fv4*)(xp_ + 32); xq[nt_][3] = *(const fv4*)(xp_ + 36);\
  } } while (0)

// ---------------------------------------------------------------------------
// Fused kernel (= verified R9 structure + uniform-granule fast path).
// 256-thread blocks; gw1/mw1 bf16 fragments (48 KB) in LDS shared by 4 waves;
// gw2 sigma-g A-fragments in 32 registers/lane. Cross-granule x prefetch.
// Gate L2 runs UNSWAPPED (A=gw2s) -> D[head][node]; E-transpose via 32
// shuffles (R10's operand-swapped direct-landing variant FAILED numerically;
// reverted). Head-mask (lcol<4) folded into ev once at transpose time.
// Fast path: 93.5% of granules have no segment boundary (__all check) ->
// single masked-ea build + 8 MFMAs, numerically identical to the slow path's
// single-run outcome. Slow path: R9 run loop, svb shuffles computed there.
// MLP L2 hoisted to finalize (linear <-> weighted segment-sum commute).
// ---------------------------------------------------------------------------
__global__ __launch_bounds__(256, 2) void fused_kernel(
    const float* __restrict__ x, const int* __restrict__ batch,
    const float* __restrict__ gw1, const float* __restrict__ mw1,
    const float* __restrict__ gw2, const float* __restrict__ prelu_a,
    const float* __restrict__ b1, float* __restrict__ denom,
    float* __restrict__ zws) {
  __shared__ unsigned short wl[24576];   // 48 KB: gw1s 32K | mw1s 16K
  const int t = threadIdx.x;

  // ---- prologue: swizzle fp32 weights -> bf16 MFMA fragments in LDS ----
#pragma unroll 4
  for (int e = t; e < 24576; e += 256) {
    const float* src = (e < 16384) ? gw1 : mw1;
    int local = (e < 16384) ? e : e - 16384;
    int j = local & 7, lane = (local >> 3) & 63, tile = local >> 9;
    int row = (tile >> 1) * 16 + (lane & 15);
    int k = (tile & 1) * 32 + ((lane >> 4) & 3) * 8 + j;
    wl[e] = f2bf(src[row * 64 + k]);
  }
  __syncthreads();   // only barrier in the kernel
  const unsigned short* gw1s = wl;
  const unsigned short* mw1s = wl + 16384;

  const int wave = t >> 6, lane = t & 63;
  const int quad = lane >> 4, lcol = lane & 15;
  const float slope = prelu_a[0];   // 0<slope<1 => prelu(v) = max(v, slope*v)
  const int W = blockIdx.x * 4 + wave;
  const int g0 = (int)(((long long)W * NG) / NWAVES);
  const int g1 = (int)(((long long)(W + 1) * NG) / NWAVES);

  // gw2 sigma-g A-fragments in registers (rows 4-15 of the 16-row tile = 0).
  short8 gareg[8];
#pragma unroll
  for (int sst = 0; sst < 8; ++sst) {
    union { short8 s; unsigned short h[8]; } u;
#pragma unroll
    for (int j = 0; j < 8; ++j) {
      int w = sst * 32 + ((j >> 2) << 4) + 4 * quad + (j & 3);
      u.h[j] = (lcol < 4) ? f2bf(gw2[lcol * 256 + w]) : (unsigned short)0;
    }
    gareg[sst] = u.s;
  }

  float b1v[8];
#pragma unroll
  for (int mt = 0; mt < 8; ++mt) b1v[mt] = b1[mt * 16 + lcol];  // bias per fcol
  const float hm = (lcol < 4) ? 1.f : 0.f;   // head mask (A rows 4-15 = 0)

  floatx4 acc[8];                       // Z accumulator: [mt] x 4 head-rows
#pragma unroll
  for (int mt = 0; mt < 8; ++mt) acc[mt] = (floatx4){0.f, 0.f, 0.f, 0.f};
  float es = 0.f;
  int fs = g0 * 32; if (fs > NN - 1) fs = NN - 1;
  int cur_seg = batch[fs];

  int svp[2]; fv4 xq[2][4];
  PREF(g0);

  union EA { unsigned u[4]; short8 s8; };

  for (int g = g0; g < g1; ++g) {
    int sv[2] = {svp[0], svp[1]};
    short8 bx[2][2];
#pragma unroll
    for (int nt = 0; nt < 2; ++nt) {    // pack prefetched x -> bf16 frags
      union { short8 s; unsigned u[4]; } u0, u1;
      u0.u[0] = cvtpk(xq[nt][0][0], xq[nt][0][1]);
      u0.u[1] = cvtpk(xq[nt][0][2], xq[nt][0][3]);
      u0.u[2] = cvtpk(xq[nt][1][0], xq[nt][1][1]);
      u0.u[3] = cvtpk(xq[nt][1][2], xq[nt][1][3]);
      u1.u[0] = cvtpk(xq[nt][2][0], xq[nt][2][1]);
      u1.u[1] = cvtpk(xq[nt][2][2], xq[nt][2][3]);
      u1.u[2] = cvtpk(xq[nt][3][0], xq[nt][3][1]);
      u1.u[3] = cvtpk(xq[nt][3][2], xq[nt][3][3]);
      bx[nt][0] = u0.s; bx[nt][1] = u1.s;
    }
    {  // issue next granule's loads NOW; latency hides under this granule
      int gn = (g + 1 < NG) ? (g + 1) : g;
      PREF(gn);
    }

    // ---- gate L1 MFMA + PReLU -> sigma-g packed B -> gate L2 MFMA ----
    floatx4 cg0 = {0.f, 0.f, 0.f, 0.f}, cg1 = {0.f, 0.f, 0.f, 0.f};
#pragma unroll
    for (int sst = 0; sst < 8; ++sst) {
      union GB { short8 s; unsigned u[4]; } gb0, gb1;
#pragma unroll
      for (int half = 0; half < 2; ++half) {
        const int mt = sst * 2 + half;
        short8 a0 = *(const short8*)(gw1s + ((size_t)(mt * 2 + 0) * 64 + lane) * 8);
        short8 a1 = *(const short8*)(gw1s + ((size_t)(mt * 2 + 1) * 64 + lane) * 8);
        floatx4 c0 = {0.f, 0.f, 0.f, 0.f};
        c0 = MFMA16(a0, bx[0][0], c0);
        c0 = MFMA16(a1, bx[0][1], c0);
        floatx4 c1 = {0.f, 0.f, 0.f, 0.f};
        c1 = MFMA16(a0, bx[1][0], c1);
        c1 = MFMA16(a1, bx[1][1], c1);
        gb0.u[half * 2 + 0] = cvtpk(fmaxf(c0[0], slope * c0[0]),
                                    fmaxf(c0[1], slope * c0[1]));
        gb0.u[half * 2 + 1] = cvtpk(fmaxf(c0[2], slope * c0[2]),
                                    fmaxf(c0[3], slope * c0[3]));
        gb1.u[half * 2 + 0] = cvtpk(fmaxf(c1[0], slope * c1[0]),
                                    fmaxf(c1[1], slope * c1[1]));
        gb1.u[half * 2 + 1] = cvtpk(fmaxf(c1[2], slope * c1[2]),
                                    fmaxf(c1[3], slope * c1[3]));
      }
      cg0 = MFMA16(gareg[sst], gb0.s, cg0);
      cg1 = MFMA16(gareg[sst], gb1.s, cg1);
    }
    float e0a[4], e1a[4];
#pragma unroll
    for (int hh = 0; hh < 4; ++hh) {
      e0a[hh] = __expf(cg0[hh]);   // |gate| small -> no running max needed
      e1a[hh] = __expf(cg1[hh]);
    }

    // ---- E-transpose (sigma-aligned): ev[e] = e(node=sigma(q*8+e), h=lcol&3)
    //      head-mask folded in: ev = 0 for lcol >= 4 ----
    float ev[8];
#pragma unroll
    for (int j = 0; j < 4; ++j) {
      int src = 4 * quad + j;
      float t0 = __shfl(e0a[0], src), t1 = __shfl(e0a[1], src);
      float t2 = __shfl(e0a[2], src), t3 = __shfl(e0a[3], src);
      float c01 = (lcol & 1) ? t1 : t0, c23 = (lcol & 1) ? t3 : t2;
      ev[j] = hm * ((lcol & 2) ? c23 : c01);
      t0 = __shfl(e1a[0], src); t1 = __shfl(e1a[1], src);
      t2 = __shfl(e1a[2], src); t3 = __shfl(e1a[3], src);
      c01 = (lcol & 1) ? t1 : t0; c23 = (lcol & 1) ? t3 : t2;
      ev[4 + j] = hm * ((lcol & 2) ? c23 : c01);
    }

    // ---- mlp1 swapped -> zb[mt] = Z-MFMA B-frags (sigma order, 0 shuffles) --
    union BH { short8 s; unsigned u[4]; } zb[8];
#pragma unroll
    for (int mt = 0; mt < 8; ++mt) {
      short8 w0 = *(const short8*)(mw1s + ((size_t)(mt * 2 + 0) * 64 + lane) * 8);
      short8 w1 = *(const short8*)(mw1s + ((size_t)(mt * 2 + 1) * 64 + lane) * 8);
      float bb = b1v[mt];
      floatx4 c0 = {0.f, 0.f, 0.f, 0.f};
      c0 = MFMA16(bx[0][0], w0, c0);      // A = x (rows=node), B = mw1 (cols=fcol)
      c0 = MFMA16(bx[0][1], w1, c0);
      floatx4 c1 = {0.f, 0.f, 0.f, 0.f};
      c1 = MFMA16(bx[1][0], w0, c1);
      c1 = MFMA16(bx[1][1], w1, c1);
      zb[mt].u[0] = cvtpk(fmaxf(c0[0] + bb, 0.f), fmaxf(c0[1] + bb, 0.f));
      zb[mt].u[1] = cvtpk(fmaxf(c0[2] + bb, 0.f), fmaxf(c0[3] + bb, 0.f));
      zb[mt].u[2] = cvtpk(fmaxf(c1[0] + bb, 0.f), fmaxf(c1[1] + bb, 0.f));
      zb[mt].u[3] = cvtpk(fmaxf(c1[2] + bb, 0.f), fmaxf(c1[3] + bb, 0.f));
    }

    // ---- segment accumulation ----
    int s0 = __shfl(sv[0], 0);          // seg of first node (uniform value)
    bool uni = __all(sv[0] == s0 && sv[1] == s0);
    if (uni) {                          // fast path: no boundary in granule
      if (s0 != cur_seg) { FLUSH(); cur_seg = s0; }
      EA ea;
#pragma unroll
      for (int jj = 0; jj < 4; ++jj) {
        ea.u[jj] = cvtpk(ev[2 * jj], ev[2 * jj + 1]);
        es += bflo(ea.u[jj]) + bfhi(ea.u[jj]);   // denom from SAME rounded e
      }
#pragma unroll
      for (int mt = 0; mt < 8; ++mt)
        acc[mt] = MFMA16(ea.s8, zb[mt].s, acc[mt]);
    } else {                            // slow path: run loop with masking
      int svb[8];
#pragma unroll
      for (int j = 0; j < 4; ++j) {     // svb[e] = seg(node sigma(q*8+e))
        svb[j]     = __shfl(sv[0], 4 * quad + j);
        svb[4 + j] = __shfl(sv[1], 4 * quad + j);
      }
      int p = 0;
      while (p < 32) {
        int selv = (p >> 4) ? sv[1] : sv[0];
        int s = __shfl(selv, p & 15);   // seg of first unprocessed node
        if (s != cur_seg) { FLUSH(); cur_seg = s; }
        int cnt = (int)__popcll(__ballot(sv[0] == s)) +
                  (int)__popcll(__ballot(sv[1] == s));
        EA ea;
#pragma unroll
        for (int jj = 0; jj < 4; ++jj) {
          float e0 = (svb[2 * jj] == s) ? ev[2 * jj] : 0.f;
          float e1 = (svb[2 * jj + 1] == s) ? ev[2 * jj + 1] : 0.f;
          ea.u[jj] = cvtpk(e0, e1);
          es += bflo(ea.u[jj]) + bfhi(ea.u[jj]);
        }
#pragma unroll
        for (int mt = 0; mt < 8; ++mt)
          acc[mt] = MFMA16(ea.s8, zb[mt].s, acc[mt]);
        p += (cnt >> 2);                // 4 quads replicate each node
      }
    }
  }
  FLUSH();
}

// ---------------------------------------------------------------------------
// Finalize (fp32, exact): out[seg,fcol] = mw2[fcol,:].Z[seg,h(fcol),:]/denom
//                                         + b2[fcol]   (h = fcol>>5)
// ---------------------------------------------------------------------------
__global__ __launch_bounds__(128) void finalize_kernel(
    const float* __restrict__ zws, const float* __restrict__ denom,
    const float* __restrict__ mw2, const float* __restrict__ b2,
    float* __restrict__ out) {
  __shared__ float zL[512];
  const int seg = blockIdx.x, t = threadIdx.x;
#pragma unroll
  for (int i = 0; i < 4; ++i) zL[t + i * 128] = zws[(size_t)seg * 512 + t + i * 128];
  __syncthreads();
  const int fcol = t, h = t >> 5;
  float d = denom[seg * 4 + h];
  const fv4* mrow = (const fv4*)(mw2 + (size_t)fcol * 128);
  const fv4* zrow = (const fv4*)(zL + h * 128);
  float a0 = 0.f, a1 = 0.f, a2 = 0.f, a3 = 0.f;
#pragma unroll 8
  for (int k = 0; k < 32; ++k) {
    fv4 w = mrow[k], z = zrow[k];
    a0 = fmaf(w[0], z[0], a0); a1 = fmaf(w[1], z[1], a1);
    a2 = fmaf(w[2], z[2], a2); a3 = fmaf(w[3], z[3], a3);
  }
  float acc = (a0 + a1) + (a2 + a3);
  out[(size_t)seg * 128 + fcol] = (d > 0.f) ? (acc / d + b2[fcol]) : 0.f;
}

// ---------------------------------------------------------------------------
extern "C" void kernel_launch(void* const* d_in, const int* in_sizes, int n_in,
                              void* d_out, int out_size, void* d_ws, size_t ws_size,
                              hipStream_t stream) {
  const float* x     = (const float*)d_in[0];
  const int*   batch = (const int*)d_in[1];
  // d_in[2] = num_segments (constant 1024, unused)
  const float* gw1 = (const float*)d_in[3];
  const float* pa  = (const float*)d_in[4];
  const float* gw2 = (const float*)d_in[5];
  const float* mw1 = (const float*)d_in[6];
  const float* mb1 = (const float*)d_in[7];
  const float* mw2 = (const float*)d_in[8];
  const float* mb2 = (const float*)d_in[9];
  float* out = (float*)d_out;

  char* ws = (char*)d_ws;
  float* denom = (float*)ws;                              // 16,384 B
  float* zws   = (float*)(ws + 16384);                    // 2,097,152 B (Z)

  // denom and zws are contiguous -> one memset launch
  hipMemsetAsync(ws, 0, 16384 + 2097152, stream);

  fused_kernel<<<NBLK, 256, 0, stream>>>(x, batch, gw1, mw1, gw2,
                                         pa, mb1, denom, zws);

  finalize_kernel<<<1024, 128, 0, stream>>>(zws, denom, mw2, mb2, out);
}